// Round 1
// baseline (676.134 us; speedup 1.0000x reference)
//
#include <hip/hip_runtime.h>
#include <hip/hip_bf16.h>

// L=2048, E=512, E_PT=300, H=16. All inputs f32. Output f32 [2048,512].
//
// Pipeline:
//  1) Y[i, h*300+e] = (x_i*w2_h)/(max(||x_i*w2_h||,eps)*sqrt(16))  -> bf16 [2048,4800]
//     (mean over heads of per-head cosine grams == single gram Y Y^T)
//  2) S = Y Y^T (f32 accum, bf16 MFMA 16x16x32, 128x128 tile, global_load_lds w=16)
//  3) borderline repair: |S-0.1| < 5e-3 entries recomputed exactly in f32
//     (threshold flip hazard: bf16 score error bounded by ~4e-3)
//  4) row softmax with >=0.1 mask -> adj bf16 [2048,2048]
//  5) GCN: T0=L@W0, X1=relu(adj@T0), T1=X1@W1, out=relu(adj@T1), all bf16 MFMA
//     via C = A * B^T gemm + tiny transpose/cast helpers.

typedef __attribute__((ext_vector_type(8))) short bf16x8;
typedef __attribute__((ext_vector_type(4))) float f32x4;

#define L_DIM 2048
#define EPT 300
#define H_DIM 16
#define KDIM 4800

// ---------------- 1) Y + norms ----------------
__global__ void compute_y_kernel(const float* __restrict__ xpt,
                                 const float* __restrict__ Wpt,
                                 __hip_bfloat16* __restrict__ Y,
                                 float* __restrict__ norms) {
  int gw = (blockIdx.x * 256 + threadIdx.x) >> 6;  // wave id = (i,h) pair
  int lane = threadIdx.x & 63;
  int i = gw >> 4, h = gw & 15;
  const float* x = xpt + i * EPT;
  const float* w = Wpt + h * EPT;
  float v[5];
  float ss = 0.f;
#pragma unroll
  for (int t = 0; t < 5; ++t) {
    int e = lane + 64 * t;
    float val = 0.f;
    if (e < EPT) {
      float we = w[e];
      val = x[e] * we * we;
    }
    v[t] = val;
    ss += val * val;
  }
#pragma unroll
  for (int o = 32; o >= 1; o >>= 1) ss += __shfl_xor(ss, o, 64);
  float n = fmaxf(sqrtf(ss), 1e-12f);
  if (lane == 0) norms[i * H_DIM + h] = n;
  float scale = 0.25f / n;  // 1/(norm*sqrt(H))
#pragma unroll
  for (int t = 0; t < 5; ++t) {
    int e = lane + 64 * t;
    if (e < EPT) Y[(size_t)i * KDIM + h * EPT + e] = __float2bfloat16(v[t] * scale);
  }
}

__global__ void w4_kernel(const float* __restrict__ Wpt, float* __restrict__ w4) {
  int i = blockIdx.x * 256 + threadIdx.x;
  if (i < H_DIM * EPT) {
    float w = Wpt[i];
    float w2 = w * w;
    w4[i] = w2 * w2;
  }
}

// ---------------- 2) bt-GEMM: C = A * B^T ----------------
// A: [M,K] bf16 row-major, B: [N,K] bf16 row-major. M,N mult of 128, K mult of 64.
template <bool RELU, bool OUT_BF16>
__global__ __launch_bounds__(256) void gemm_bt(const __hip_bfloat16* __restrict__ A,
                                               const __hip_bfloat16* __restrict__ B,
                                               void* __restrict__ Cv, int M, int N, int K) {
  __shared__ __attribute__((aligned(16))) __hip_bfloat16 As[128 * 64];
  __shared__ __attribute__((aligned(16))) __hip_bfloat16 Bs[128 * 64];
  const int tid = threadIdx.x;
  const int lane = tid & 63;
  const int wave = tid >> 6;
  const int wm = wave >> 1, wn = wave & 1;
  const int r = lane & 15, q = lane >> 4;
  const int row0 = blockIdx.y * 128, col0 = blockIdx.x * 128;

  f32x4 acc[4][4];
#pragma unroll
  for (int a = 0; a < 4; ++a)
#pragma unroll
    for (int b = 0; b < 4; ++b) {
      f32x4 z = {0.f, 0.f, 0.f, 0.f};
      acc[a][b] = z;
    }

  const int frow = tid >> 3;        // 0..31
  const int fcol = (tid & 7) * 8;   // 8-elt (16B) chunk within 64-wide k tile

  for (int k0 = 0; k0 < K; k0 += 64) {
#pragma unroll
    for (int it = 0; it < 4; ++it) {
      int rr = it * 32 + frow;
      __builtin_amdgcn_global_load_lds(
          (const __attribute__((address_space(1))) void*)(A + (size_t)(row0 + rr) * K + k0 + fcol),
          (__attribute__((address_space(3))) void*)(As + (it * 256 + tid) * 8), 16, 0, 0);
      __builtin_amdgcn_global_load_lds(
          (const __attribute__((address_space(1))) void*)(B + (size_t)(col0 + rr) * K + k0 + fcol),
          (__attribute__((address_space(3))) void*)(Bs + (it * 256 + tid) * 8), 16, 0, 0);
    }
    __syncthreads();
#pragma unroll
    for (int kk = 0; kk < 2; ++kk) {
      bf16x8 af[4], bfr[4];
#pragma unroll
      for (int t = 0; t < 4; ++t) {
        af[t] = *(const bf16x8*)(As + (wm * 64 + t * 16 + r) * 64 + kk * 32 + q * 8);
        bfr[t] = *(const bf16x8*)(Bs + (wn * 64 + t * 16 + r) * 64 + kk * 32 + q * 8);
      }
#pragma unroll
      for (int tm = 0; tm < 4; ++tm)
#pragma unroll
        for (int tn = 0; tn < 4; ++tn)
          acc[tm][tn] = __builtin_amdgcn_mfma_f32_16x16x32_bf16(af[tm], bfr[tn], acc[tm][tn], 0, 0, 0);
    }
    __syncthreads();
  }
  // C/D layout: col = lane&15, row = (lane>>4)*4 + reg   [guide §3, m89-verified]
#pragma unroll
  for (int tm = 0; tm < 4; ++tm) {
    int gr0 = row0 + wm * 64 + tm * 16 + q * 4;
#pragma unroll
    for (int tn = 0; tn < 4; ++tn) {
      int gc = col0 + wn * 64 + tn * 16 + r;
#pragma unroll
      for (int p = 0; p < 4; ++p) {
        float vv = acc[tm][tn][p];
        if (RELU) vv = fmaxf(vv, 0.f);
        if (OUT_BF16)
          ((__hip_bfloat16*)Cv)[(size_t)(gr0 + p) * N + gc] = __float2bfloat16(vv);
        else
          ((float*)Cv)[(size_t)(gr0 + p) * N + gc] = vv;
      }
    }
  }
}

// ---------------- 3) exact f32 repair of borderline scores ----------------
__global__ void fix_borderline(float* __restrict__ S, const float* __restrict__ xpt,
                               const float* __restrict__ w4, const float* __restrict__ norms) {
  const int tid = threadIdx.x;
  const int lane = tid & 63;
  long long wid = (long long)((blockIdx.x * 256 + tid) >> 6);
  size_t base = (size_t)wid * 64;
  float sv = S[base + lane];
  unsigned long long mask = __ballot(fabsf(sv - 0.1f) < 5e-3f);
  while (mask) {
    int l = __ffsll(mask) - 1;
    mask &= mask - 1;
    size_t e = base + (size_t)l;
    int i = (int)(e >> 11), j = (int)(e & 2047);
    const float* xi = xpt + i * EPT;
    const float* xj = xpt + j * EPT;
    float xiv[5], xjv[5];
#pragma unroll
    for (int t = 0; t < 5; ++t) {
      int idx = lane + 64 * t;
      xiv[t] = idx < EPT ? xi[idx] : 0.f;
      xjv[t] = idx < EPT ? xj[idx] : 0.f;
    }
    float accv = 0.f;
#pragma unroll
    for (int h = 0; h < H_DIM; ++h) {
      float ph = 0.f;
#pragma unroll
      for (int t = 0; t < 5; ++t) {
        int idx = lane + 64 * t;
        if (idx < EPT) ph += xiv[t] * xjv[t] * w4[h * EPT + idx];
      }
      float invn = 1.f / (norms[i * H_DIM + h] * norms[j * H_DIM + h]);
      accv += ph * invn;
    }
#pragma unroll
    for (int o = 32; o >= 1; o >>= 1) accv += __shfl_xor(accv, o, 64);
    if (lane == 0) S[e] = accv * (1.f / 16.f);
  }
}

// ---------------- 4) thresholded row softmax -> bf16 adj ----------------
__global__ void softmax_kernel(const float* __restrict__ S, __hip_bfloat16* __restrict__ adj) {
  __shared__ float red[4];
  const int row = blockIdx.x;
  const float* s = S + (size_t)row * L_DIM;
  const int tid = threadIdx.x;
  float m = -1e30f;
  for (int j = tid; j < L_DIM; j += 256) {
    float v = s[j];
    if (v >= 0.1f && v > m) m = v;
  }
#pragma unroll
  for (int o = 32; o >= 1; o >>= 1) m = fmaxf(m, __shfl_xor(m, o, 64));
  if ((tid & 63) == 0) red[tid >> 6] = m;
  __syncthreads();
  m = fmaxf(fmaxf(red[0], red[1]), fmaxf(red[2], red[3]));
  float sum = 0.f;
  for (int j = tid; j < L_DIM; j += 256) {
    float v = s[j];
    if (v >= 0.1f) sum += __expf(v - m);
  }
#pragma unroll
  for (int o = 32; o >= 1; o >>= 1) sum += __shfl_xor(sum, o, 64);
  __syncthreads();
  if ((tid & 63) == 0) red[tid >> 6] = sum;
  __syncthreads();
  sum = red[0] + red[1] + red[2] + red[3];
  float inv = 1.f / sum;
  for (int j = tid; j < L_DIM; j += 256) {
    float v = s[j];
    float a = (v >= 0.1f) ? __expf(v - m) * inv : 0.f;
    adj[(size_t)row * L_DIM + j] = __float2bfloat16(a);
  }
}

// ---------------- helpers ----------------
__global__ void cast_bf16_kernel(const float* __restrict__ in, __hip_bfloat16* __restrict__ out,
                                 int n) {
  int i = blockIdx.x * 256 + threadIdx.x;
  if (i < n) out[i] = __float2bfloat16(in[i]);
}

template <typename T>
__global__ void transpose_bf16_kernel(const T* __restrict__ in, __hip_bfloat16* __restrict__ out,
                                      int R, int C) {
  __shared__ float tile[32][33];
  int c0 = blockIdx.x * 32, r0 = blockIdx.y * 32;
  int tx = threadIdx.x, ty = threadIdx.y;
  for (int i = ty; i < 32; i += 8) tile[i][tx] = (float)in[(size_t)(r0 + i) * C + c0 + tx];
  __syncthreads();
  for (int i = ty; i < 32; i += 8)
    out[(size_t)(c0 + i) * R + r0 + tx] = __float2bfloat16(tile[tx][i]);
}

extern "C" void kernel_launch(void* const* d_in, const int* in_sizes, int n_in, void* d_out,
                              int out_size, void* d_ws, size_t ws_size, hipStream_t stream) {
  const float* label = (const float*)d_in[0];  // [2048,512]
  const float* xpt = (const float*)d_in[1];    // [2048,300]
  const float* Wpt = (const float*)d_in[2];    // [16,300]
  const float* W0 = (const float*)d_in[3];     // [512,512]
  const float* W1 = (const float*)d_in[4];     // [512,512]
  float* out = (float*)d_out;                  // [2048,512]

  char* ws = (char*)d_ws;
  __hip_bfloat16* Y = (__hip_bfloat16*)ws;              // 19,660,800 B
  float* S = (float*)(ws + 19660800);                   // 16,777,216 B
  float* norms = (float*)(ws + 36438016);               // 131,072 B
  float* w4 = (float*)(ws + 36569088);                  // 19,200 B
  __hip_bfloat16* adj = (__hip_bfloat16*)ws;            // reuses Y region (8.4 MB)
  char* tmp = ws + 19660800;                            // reuses S region after softmax
  __hip_bfloat16* Lbf = (__hip_bfloat16*)tmp;
  __hip_bfloat16* W0t = (__hip_bfloat16*)(tmp + 2097152);
  __hip_bfloat16* W1t = (__hip_bfloat16*)(tmp + 2621440);
  __hip_bfloat16* T0 = (__hip_bfloat16*)(tmp + 3145728);
  __hip_bfloat16* T0t = (__hip_bfloat16*)(tmp + 5242880);
  __hip_bfloat16* X1 = (__hip_bfloat16*)(tmp + 7340032);
  __hip_bfloat16* T1 = (__hip_bfloat16*)(tmp + 9437184);
  __hip_bfloat16* T1t = (__hip_bfloat16*)(tmp + 11534336);

  compute_y_kernel<<<8192, 256, 0, stream>>>(xpt, Wpt, Y, norms);
  w4_kernel<<<19, 256, 0, stream>>>(Wpt, w4);
  // S = Y Y^T  [2048,2048]
  gemm_bt<false, false><<<dim3(16, 16), 256, 0, stream>>>(Y, Y, S, 2048, 2048, KDIM);
  fix_borderline<<<16384, 256, 0, stream>>>(S, xpt, w4, norms);
  softmax_kernel<<<2048, 256, 0, stream>>>(S, adj);  // adj overwrites Y region (Y dead)
  // GCN prep (runs after softmax: writes into S region)
  cast_bf16_kernel<<<4096, 256, 0, stream>>>(label, Lbf, 2048 * 512);
  transpose_bf16_kernel<float><<<dim3(16, 16), dim3(32, 8), 0, stream>>>(W0, W0t, 512, 512);
  transpose_bf16_kernel<float><<<dim3(16, 16), dim3(32, 8), 0, stream>>>(W1, W1t, 512, 512);
  // T0 = label @ W0
  gemm_bt<false, true><<<dim3(4, 16), 256, 0, stream>>>(Lbf, W0t, T0, 2048, 512, 512);
  transpose_bf16_kernel<__hip_bfloat16><<<dim3(16, 64), dim3(32, 8), 0, stream>>>(T0, T0t, 2048, 512);
  // X1 = relu(adj @ T0)
  gemm_bt<true, true><<<dim3(4, 16), 256, 0, stream>>>(adj, T0t, X1, 2048, 512, 2048);
  // T1 = X1 @ W1
  gemm_bt<false, true><<<dim3(4, 16), 256, 0, stream>>>(X1, W1t, T1, 2048, 512, 512);
  transpose_bf16_kernel<__hip_bfloat16><<<dim3(16, 64), dim3(32, 8), 0, stream>>>(T1, T1t, 2048, 512);
  // out = relu(adj @ T1)
  gemm_bt<true, false><<<dim3(4, 16), 256, 0, stream>>>(adj, T1t, out, 2048, 512, 2048);
}

// Round 2
// 646.289 us; speedup vs baseline: 1.0462x; 1.0462x over previous
//
#include <hip/hip_runtime.h>
#include <hip/hip_bf16.h>

// L=2048, E=512, E_PT=300, H=16. All inputs f32. Output f32 [2048,512].
//
// Pipeline:
//  1) Y[i, h*300+e] = (x_i*w2_h)/(max(||x_i*w2_h||,eps)*sqrt(16))  -> bf16 [2048,4800]
//  2) S = Y Y^T, symmetric: compute upper-triangle blocks only, mirror-store
//  3) borderline repair, 2-phase: ballot-compact indices with |S-0.1|<1.5e-3
//     (~11 sigma of bf16 gram error; hard bound 3.9e-3, realistic max ~8e-4),
//     then load-balanced exact-f32 recompute over the compacted list
//  4) row softmax with >=0.1 mask -> adj bf16
//  5) GCN: T0=L@W0, X1=relu(adj@T0), T1=X1@W1, out=relu(adj@T1), bf16 MFMA

typedef __attribute__((ext_vector_type(8))) short bf16x8;
typedef __attribute__((ext_vector_type(4))) float f32x4;

#define L_DIM 2048
#define EPT 300
#define H_DIM 16
#define KDIM 4800
#define WINDOW 1.5e-3f
#define LIST_CAP 2500000

// ---------------- 1) Y + norms ----------------
__global__ void compute_y_kernel(const float* __restrict__ xpt,
                                 const float* __restrict__ Wpt,
                                 __hip_bfloat16* __restrict__ Y,
                                 float* __restrict__ norms) {
  int gw = (blockIdx.x * 256 + threadIdx.x) >> 6;  // wave id = (i,h) pair
  int lane = threadIdx.x & 63;
  int i = gw >> 4, h = gw & 15;
  const float* x = xpt + i * EPT;
  const float* w = Wpt + h * EPT;
  float v[5];
  float ss = 0.f;
#pragma unroll
  for (int t = 0; t < 5; ++t) {
    int e = lane + 64 * t;
    float val = 0.f;
    if (e < EPT) {
      float we = w[e];
      val = x[e] * we * we;
    }
    v[t] = val;
    ss += val * val;
  }
#pragma unroll
  for (int o = 32; o >= 1; o >>= 1) ss += __shfl_xor(ss, o, 64);
  float n = fmaxf(sqrtf(ss), 1e-12f);
  if (lane == 0) norms[i * H_DIM + h] = n;
  float scale = 0.25f / n;  // 1/(norm*sqrt(H))
#pragma unroll
  for (int t = 0; t < 5; ++t) {
    int e = lane + 64 * t;
    if (e < EPT) Y[(size_t)i * KDIM + h * EPT + e] = __float2bfloat16(v[t] * scale);
  }
}

__global__ void w4_kernel(const float* __restrict__ Wpt, float* __restrict__ w4) {
  int i = blockIdx.x * 256 + threadIdx.x;
  if (i < H_DIM * EPT) {
    float w = Wpt[i];
    float w2 = w * w;
    w4[i] = w2 * w2;
  }
}

// ---------------- 2) bt-GEMM: C = A * B^T ----------------
// A: [M,K] bf16 row-major, B: [N,K] bf16 row-major. M,N mult of 128, K mult of 64.
// MIRROR: square symmetric output — skip lower-tri blocks, mirror-store upper.
template <bool RELU, bool OUT_BF16, bool MIRROR>
__global__ __launch_bounds__(256) void gemm_bt(const __hip_bfloat16* __restrict__ A,
                                               const __hip_bfloat16* __restrict__ B,
                                               void* __restrict__ Cv, int M, int N, int K) {
  const int row0 = blockIdx.y * 128, col0 = blockIdx.x * 128;
  if (MIRROR && col0 < row0) return;
  __shared__ __attribute__((aligned(16))) __hip_bfloat16 As[128 * 64];
  __shared__ __attribute__((aligned(16))) __hip_bfloat16 Bs[128 * 64];
  const int tid = threadIdx.x;
  const int lane = tid & 63;
  const int wave = tid >> 6;
  const int wm = wave >> 1, wn = wave & 1;
  const int r = lane & 15, q = lane >> 4;

  f32x4 acc[4][4];
#pragma unroll
  for (int a = 0; a < 4; ++a)
#pragma unroll
    for (int b = 0; b < 4; ++b) {
      f32x4 z = {0.f, 0.f, 0.f, 0.f};
      acc[a][b] = z;
    }

  const int frow = tid >> 3;        // 0..31
  const int fcol = (tid & 7) * 8;   // 8-elt (16B) chunk within 64-wide k tile

  for (int k0 = 0; k0 < K; k0 += 64) {
#pragma unroll
    for (int it = 0; it < 4; ++it) {
      int rr = it * 32 + frow;
      __builtin_amdgcn_global_load_lds(
          (const __attribute__((address_space(1))) void*)(A + (size_t)(row0 + rr) * K + k0 + fcol),
          (__attribute__((address_space(3))) void*)(As + (it * 256 + tid) * 8), 16, 0, 0);
      __builtin_amdgcn_global_load_lds(
          (const __attribute__((address_space(1))) void*)(B + (size_t)(col0 + rr) * K + k0 + fcol),
          (__attribute__((address_space(3))) void*)(Bs + (it * 256 + tid) * 8), 16, 0, 0);
    }
    __syncthreads();
#pragma unroll
    for (int kk = 0; kk < 2; ++kk) {
      bf16x8 af[4], bfr[4];
#pragma unroll
      for (int t = 0; t < 4; ++t) {
        af[t] = *(const bf16x8*)(As + (wm * 64 + t * 16 + r) * 64 + kk * 32 + q * 8);
        bfr[t] = *(const bf16x8*)(Bs + (wn * 64 + t * 16 + r) * 64 + kk * 32 + q * 8);
      }
#pragma unroll
      for (int tm = 0; tm < 4; ++tm)
#pragma unroll
        for (int tn = 0; tn < 4; ++tn)
          acc[tm][tn] = __builtin_amdgcn_mfma_f32_16x16x32_bf16(af[tm], bfr[tn], acc[tm][tn], 0, 0, 0);
    }
    __syncthreads();
  }
  // C/D layout: col = lane&15, row = (lane>>4)*4 + reg   [guide §3, m89-verified]
#pragma unroll
  for (int tm = 0; tm < 4; ++tm) {
    int gr0 = row0 + wm * 64 + tm * 16 + q * 4;
#pragma unroll
    for (int tn = 0; tn < 4; ++tn) {
      int gc = col0 + wn * 64 + tn * 16 + r;
#pragma unroll
      for (int p = 0; p < 4; ++p) {
        float vv = acc[tm][tn][p];
        if (RELU) vv = fmaxf(vv, 0.f);
        if (OUT_BF16)
          ((__hip_bfloat16*)Cv)[(size_t)(gr0 + p) * N + gc] = __float2bfloat16(vv);
        else {
          ((float*)Cv)[(size_t)(gr0 + p) * N + gc] = vv;
          if (MIRROR && col0 > row0) ((float*)Cv)[(size_t)gc * N + (gr0 + p)] = vv;
        }
      }
    }
  }
}

// ---------------- 3a) scan: compact borderline indices ----------------
__global__ void scan_borderline(const float* __restrict__ S, int* __restrict__ count,
                                int* __restrict__ list) {
  const int lane = threadIdx.x & 63;
  int idx0 = blockIdx.x * 256 + threadIdx.x;
  const int stride = gridDim.x * 256;
  for (int idx = idx0; idx < L_DIM * L_DIM; idx += stride) {
    float v = S[idx];
    bool b = fabsf(v - 0.1f) < WINDOW;
    unsigned long long m = __ballot(b);
    if (m) {
      int base = 0;
      if (lane == 0) base = atomicAdd(count, __popcll(m));
      base = __shfl(base, 0, 64);
      if (b) {
        int pos = base + __popcll(m & ((1ull << lane) - 1ull));
        if (pos < LIST_CAP) list[pos] = idx;
      }
    }
  }
}

// ---------------- 3b) exact f32 repair over compacted list ----------------
__global__ void repair_borderline(float* __restrict__ S, const int* __restrict__ count,
                                  const int* __restrict__ list, const float* __restrict__ xpt,
                                  const float* __restrict__ w4, const float* __restrict__ norms) {
  const int lane = threadIdx.x & 63;
  const int wid = (blockIdx.x * 256 + threadIdx.x) >> 6;
  const int nw = gridDim.x * 4;
  int n = *count;
  if (n > LIST_CAP) n = LIST_CAP;
  for (int k = wid; k < n; k += nw) {
    int e = list[k];
    int i = e >> 11, j = e & 2047;
    const float* xi = xpt + i * EPT;
    const float* xj = xpt + j * EPT;
    float xiv[5], xjv[5];
#pragma unroll
    for (int t = 0; t < 5; ++t) {
      int idx = lane + 64 * t;
      xiv[t] = idx < EPT ? xi[idx] : 0.f;
      xjv[t] = idx < EPT ? xj[idx] : 0.f;
    }
    float accv = 0.f;
#pragma unroll
    for (int h = 0; h < H_DIM; ++h) {
      float ph = 0.f;
#pragma unroll
      for (int t = 0; t < 5; ++t) {
        int idx = lane + 64 * t;
        if (idx < EPT) ph += xiv[t] * xjv[t] * w4[h * EPT + idx];
      }
      float invn = 1.f / (norms[i * H_DIM + h] * norms[j * H_DIM + h]);
      accv += ph * invn;
    }
#pragma unroll
    for (int o = 32; o >= 1; o >>= 1) accv += __shfl_xor(accv, o, 64);
    if (lane == 0) S[e] = accv * (1.f / 16.f);
  }
}

// ---------------- 4) thresholded row softmax -> bf16 adj ----------------
__global__ void softmax_kernel(const float* __restrict__ S, __hip_bfloat16* __restrict__ adj) {
  __shared__ float red[4];
  const int row = blockIdx.x;
  const float* s = S + (size_t)row * L_DIM;
  const int tid = threadIdx.x;
  float m = -1e30f;
  for (int j = tid; j < L_DIM; j += 256) {
    float v = s[j];
    if (v >= 0.1f && v > m) m = v;
  }
#pragma unroll
  for (int o = 32; o >= 1; o >>= 1) m = fmaxf(m, __shfl_xor(m, o, 64));
  if ((tid & 63) == 0) red[tid >> 6] = m;
  __syncthreads();
  m = fmaxf(fmaxf(red[0], red[1]), fmaxf(red[2], red[3]));
  float sum = 0.f;
  for (int j = tid; j < L_DIM; j += 256) {
    float v = s[j];
    if (v >= 0.1f) sum += __expf(v - m);
  }
#pragma unroll
  for (int o = 32; o >= 1; o >>= 1) sum += __shfl_xor(sum, o, 64);
  __syncthreads();
  if ((tid & 63) == 0) red[tid >> 6] = sum;
  __syncthreads();
  sum = red[0] + red[1] + red[2] + red[3];
  float inv = 1.f / sum;
  for (int j = tid; j < L_DIM; j += 256) {
    float v = s[j];
    float a = (v >= 0.1f) ? __expf(v - m) * inv : 0.f;
    adj[(size_t)row * L_DIM + j] = __float2bfloat16(a);
  }
}

// ---------------- helpers ----------------
__global__ void cast_bf16_kernel(const float* __restrict__ in, __hip_bfloat16* __restrict__ out,
                                 int n) {
  int i = blockIdx.x * 256 + threadIdx.x;
  if (i < n) out[i] = __float2bfloat16(in[i]);
}

template <typename T>
__global__ void transpose_bf16_kernel(const T* __restrict__ in, __hip_bfloat16* __restrict__ out,
                                      int R, int C) {
  __shared__ float tile[32][33];
  int c0 = blockIdx.x * 32, r0 = blockIdx.y * 32;
  int tx = threadIdx.x, ty = threadIdx.y;
  for (int i = ty; i < 32; i += 8) tile[i][tx] = (float)in[(size_t)(r0 + i) * C + c0 + tx];
  __syncthreads();
  for (int i = ty; i < 32; i += 8)
    out[(size_t)(c0 + i) * R + r0 + tx] = __float2bfloat16(tile[tx][i]);
}

extern "C" void kernel_launch(void* const* d_in, const int* in_sizes, int n_in, void* d_out,
                              int out_size, void* d_ws, size_t ws_size, hipStream_t stream) {
  const float* label = (const float*)d_in[0];  // [2048,512]
  const float* xpt = (const float*)d_in[1];    // [2048,300]
  const float* Wpt = (const float*)d_in[2];    // [16,300]
  const float* W0 = (const float*)d_in[3];     // [512,512]
  const float* W1 = (const float*)d_in[4];     // [512,512]
  float* out = (float*)d_out;                  // [2048,512]

  char* ws = (char*)d_ws;
  __hip_bfloat16* Y = (__hip_bfloat16*)ws;              // [0, 19,660,800)
  float* S = (float*)(ws + 19660800);                   // 16,777,216 B
  float* norms = (float*)(ws + 36438016);               // 131,072 B
  float* w4 = (float*)(ws + 36569088);                  // 19,200 B
  // borderline list lives in the Y region ABOVE adj's 8.39 MB (Y dead after gram,
  // adj only uses [0, 8388608))
  int* bl_count = (int*)(ws + 9437184);
  int* bl_list = (int*)(ws + 9437696);                  // cap 2.5M ints, ends < 19.66MB
  __hip_bfloat16* adj = (__hip_bfloat16*)ws;            // reuses Y region
  char* tmp = ws + 19660800;                            // reuses S region after softmax
  __hip_bfloat16* Lbf = (__hip_bfloat16*)tmp;
  __hip_bfloat16* W0t = (__hip_bfloat16*)(tmp + 2097152);
  __hip_bfloat16* W1t = (__hip_bfloat16*)(tmp + 2621440);
  __hip_bfloat16* T0 = (__hip_bfloat16*)(tmp + 3145728);
  __hip_bfloat16* T0t = (__hip_bfloat16*)(tmp + 5242880);
  __hip_bfloat16* X1 = (__hip_bfloat16*)(tmp + 7340032);
  __hip_bfloat16* T1 = (__hip_bfloat16*)(tmp + 9437184);
  __hip_bfloat16* T1t = (__hip_bfloat16*)(tmp + 11534336);

  compute_y_kernel<<<8192, 256, 0, stream>>>(xpt, Wpt, Y, norms);
  w4_kernel<<<19, 256, 0, stream>>>(Wpt, w4);
  // S = Y Y^T  [2048,2048], symmetric (upper blocks + mirror)
  gemm_bt<false, false, true><<<dim3(16, 16), 256, 0, stream>>>(Y, Y, S, 2048, 2048, KDIM);
  // borderline: compact then repair (load-balanced)
  hipMemsetAsync(bl_count, 0, 4, stream);
  scan_borderline<<<2048, 256, 0, stream>>>(S, bl_count, bl_list);
  repair_borderline<<<2048, 256, 0, stream>>>(S, bl_count, bl_list, xpt, w4, norms);
  softmax_kernel<<<2048, 256, 0, stream>>>(S, adj);  // adj overwrites Y region (Y dead)
  // GCN prep (runs after softmax: writes into S region)
  cast_bf16_kernel<<<4096, 256, 0, stream>>>(label, Lbf, 2048 * 512);
  transpose_bf16_kernel<float><<<dim3(16, 16), dim3(32, 8), 0, stream>>>(W0, W0t, 512, 512);
  transpose_bf16_kernel<float><<<dim3(16, 16), dim3(32, 8), 0, stream>>>(W1, W1t, 512, 512);
  // T0 = label @ W0
  gemm_bt<false, true, false><<<dim3(4, 16), 256, 0, stream>>>(Lbf, W0t, T0, 2048, 512, 512);
  transpose_bf16_kernel<__hip_bfloat16><<<dim3(16, 64), dim3(32, 8), 0, stream>>>(T0, T0t, 2048, 512);
  // X1 = relu(adj @ T0)
  gemm_bt<true, true, false><<<dim3(4, 16), 256, 0, stream>>>(adj, T0t, X1, 2048, 512, 2048);
  // T1 = X1 @ W1
  gemm_bt<false, true, false><<<dim3(4, 16), 256, 0, stream>>>(X1, W1t, T1, 2048, 512, 512);
  transpose_bf16_kernel<__hip_bfloat16><<<dim3(16, 64), dim3(32, 8), 0, stream>>>(T1, T1t, 2048, 512);
  // out = relu(adj @ T1)
  gemm_bt<true, false, false><<<dim3(4, 16), 256, 0, stream>>>(adj, T1t, out, 2048, 512, 2048);
}

// Round 3
// 427.748 us; speedup vs baseline: 1.5807x; 1.5109x over previous
//
#include <hip/hip_runtime.h>
#include <hip/hip_bf16.h>

// L=2048, E=512, E_PT=300, H=16. All inputs f32. Output f32 [2048,512].
//
// Pipeline:
//  1) Y[i, h*300+e] = (x_i*w2_h)/(max(||x_i*w2_h||,eps)*sqrt(16))  -> bf16 [2048,4800]
//  2) S = Y Y^T, symmetric: compute upper-triangle blocks only, mirror-store
//  3) borderline repair, 2-phase: per-block LDS-compacted scan of |S-0.1|<1.5e-3
//     (ONE global atomic per block — R2's per-wave same-address atomic chain
//     serialized at ~24cyc each = 244us), then load-balanced exact-f32 recompute
//  4) row softmax with >=0.1 mask -> adj bf16
//  5) GCN: T0=L@W0, X1=relu(adj@T0), T1=X1@W1, out=relu(adj@T1), bf16 MFMA

typedef __attribute__((ext_vector_type(8))) short bf16x8;
typedef __attribute__((ext_vector_type(4))) float f32x4;

#define L_DIM 2048
#define EPT 300
#define H_DIM 16
#define KDIM 4800
#define WINDOW 1.5e-3f
#define LIST_CAP 2500000

// ---------------- 1) Y + norms ----------------
__global__ void compute_y_kernel(const float* __restrict__ xpt,
                                 const float* __restrict__ Wpt,
                                 __hip_bfloat16* __restrict__ Y,
                                 float* __restrict__ norms) {
  int gw = (blockIdx.x * 256 + threadIdx.x) >> 6;  // wave id = (i,h) pair
  int lane = threadIdx.x & 63;
  int i = gw >> 4, h = gw & 15;
  const float* x = xpt + i * EPT;
  const float* w = Wpt + h * EPT;
  float v[5];
  float ss = 0.f;
#pragma unroll
  for (int t = 0; t < 5; ++t) {
    int e = lane + 64 * t;
    float val = 0.f;
    if (e < EPT) {
      float we = w[e];
      val = x[e] * we * we;
    }
    v[t] = val;
    ss += val * val;
  }
#pragma unroll
  for (int o = 32; o >= 1; o >>= 1) ss += __shfl_xor(ss, o, 64);
  float n = fmaxf(sqrtf(ss), 1e-12f);
  if (lane == 0) norms[i * H_DIM + h] = n;
  float scale = 0.25f / n;  // 1/(norm*sqrt(H))
#pragma unroll
  for (int t = 0; t < 5; ++t) {
    int e = lane + 64 * t;
    if (e < EPT) Y[(size_t)i * KDIM + h * EPT + e] = __float2bfloat16(v[t] * scale);
  }
}

__global__ void w4_kernel(const float* __restrict__ Wpt, float* __restrict__ w4) {
  int i = blockIdx.x * 256 + threadIdx.x;
  if (i < H_DIM * EPT) {
    float w = Wpt[i];
    float w2 = w * w;
    w4[i] = w2 * w2;
  }
}

// ---------------- 2) bt-GEMM: C = A * B^T ----------------
// A: [M,K] bf16 row-major, B: [N,K] bf16 row-major. M,N mult of 128, K mult of 64.
// MIRROR: square symmetric output — skip lower-tri blocks, mirror-store upper.
template <bool RELU, bool OUT_BF16, bool MIRROR>
__global__ __launch_bounds__(256) void gemm_bt(const __hip_bfloat16* __restrict__ A,
                                               const __hip_bfloat16* __restrict__ B,
                                               void* __restrict__ Cv, int M, int N, int K) {
  const int row0 = blockIdx.y * 128, col0 = blockIdx.x * 128;
  if (MIRROR && col0 < row0) return;
  __shared__ __attribute__((aligned(16))) __hip_bfloat16 As[128 * 64];
  __shared__ __attribute__((aligned(16))) __hip_bfloat16 Bs[128 * 64];
  const int tid = threadIdx.x;
  const int lane = tid & 63;
  const int wave = tid >> 6;
  const int wm = wave >> 1, wn = wave & 1;
  const int r = lane & 15, q = lane >> 4;

  f32x4 acc[4][4];
#pragma unroll
  for (int a = 0; a < 4; ++a)
#pragma unroll
    for (int b = 0; b < 4; ++b) {
      f32x4 z = {0.f, 0.f, 0.f, 0.f};
      acc[a][b] = z;
    }

  const int frow = tid >> 3;        // 0..31
  const int fcol = (tid & 7) * 8;   // 8-elt (16B) chunk within 64-wide k tile

  for (int k0 = 0; k0 < K; k0 += 64) {
#pragma unroll
    for (int it = 0; it < 4; ++it) {
      int rr = it * 32 + frow;
      __builtin_amdgcn_global_load_lds(
          (const __attribute__((address_space(1))) void*)(A + (size_t)(row0 + rr) * K + k0 + fcol),
          (__attribute__((address_space(3))) void*)(As + (it * 256 + tid) * 8), 16, 0, 0);
      __builtin_amdgcn_global_load_lds(
          (const __attribute__((address_space(1))) void*)(B + (size_t)(col0 + rr) * K + k0 + fcol),
          (__attribute__((address_space(3))) void*)(Bs + (it * 256 + tid) * 8), 16, 0, 0);
    }
    __syncthreads();
#pragma unroll
    for (int kk = 0; kk < 2; ++kk) {
      bf16x8 af[4], bfr[4];
#pragma unroll
      for (int t = 0; t < 4; ++t) {
        af[t] = *(const bf16x8*)(As + (wm * 64 + t * 16 + r) * 64 + kk * 32 + q * 8);
        bfr[t] = *(const bf16x8*)(Bs + (wn * 64 + t * 16 + r) * 64 + kk * 32 + q * 8);
      }
#pragma unroll
      for (int tm = 0; tm < 4; ++tm)
#pragma unroll
        for (int tn = 0; tn < 4; ++tn)
          acc[tm][tn] = __builtin_amdgcn_mfma_f32_16x16x32_bf16(af[tm], bfr[tn], acc[tm][tn], 0, 0, 0);
    }
    __syncthreads();
  }
  // C/D layout: col = lane&15, row = (lane>>4)*4 + reg   [guide §3, m89-verified]
#pragma unroll
  for (int tm = 0; tm < 4; ++tm) {
    int gr0 = row0 + wm * 64 + tm * 16 + q * 4;
#pragma unroll
    for (int tn = 0; tn < 4; ++tn) {
      int gc = col0 + wn * 64 + tn * 16 + r;
#pragma unroll
      for (int p = 0; p < 4; ++p) {
        float vv = acc[tm][tn][p];
        if (RELU) vv = fmaxf(vv, 0.f);
        if (OUT_BF16)
          ((__hip_bfloat16*)Cv)[(size_t)(gr0 + p) * N + gc] = __float2bfloat16(vv);
        else {
          ((float*)Cv)[(size_t)(gr0 + p) * N + gc] = vv;
          if (MIRROR && col0 > row0) ((float*)Cv)[(size_t)gc * N + (gr0 + p)] = vv;
        }
      }
    }
  }
}

// ---------------- 3a) scan: per-block LDS compaction, 1 global atomic/block ----
// Each block scans exactly 2048 contiguous floats (2x float4/thread).
__global__ __launch_bounds__(256) void scan_borderline(const float* __restrict__ S,
                                                       int* __restrict__ count,
                                                       int* __restrict__ list) {
  __shared__ int lqueue[2048];
  __shared__ int lcount;
  __shared__ int gbase;
  if (threadIdx.x == 0) lcount = 0;
  __syncthreads();
  const int base_idx = blockIdx.x * 2048;
#pragma unroll
  for (int t = 0; t < 2; ++t) {
    int idx = base_idx + t * 1024 + threadIdx.x * 4;
    float4 v = *(const float4*)(S + idx);
    float vv[4] = {v.x, v.y, v.z, v.w};
#pragma unroll
    for (int u = 0; u < 4; ++u) {
      if (fabsf(vv[u] - 0.1f) < WINDOW) {
        int p = atomicAdd(&lcount, 1);  // LDS atomic — cheap
        lqueue[p] = idx + u;
      }
    }
  }
  __syncthreads();
  if (threadIdx.x == 0) gbase = atomicAdd(count, lcount);
  __syncthreads();
  int n = lcount, g0 = gbase;
  for (int k = threadIdx.x; k < n; k += 256) {
    int pos = g0 + k;
    if (pos < LIST_CAP) list[pos] = lqueue[k];
  }
}

// ---------------- 3b) exact f32 repair over compacted list ----------------
__global__ void repair_borderline(float* __restrict__ S, const int* __restrict__ count,
                                  const int* __restrict__ list, const float* __restrict__ xpt,
                                  const float* __restrict__ w4, const float* __restrict__ norms) {
  const int lane = threadIdx.x & 63;
  const int wid = (blockIdx.x * 256 + threadIdx.x) >> 6;
  const int nw = gridDim.x * 4;
  int n = *count;
  if (n > LIST_CAP) n = LIST_CAP;
  for (int k = wid; k < n; k += nw) {
    int e = list[k];
    int i = e >> 11, j = e & 2047;
    const float* xi = xpt + i * EPT;
    const float* xj = xpt + j * EPT;
    float xiv[5], xjv[5];
#pragma unroll
    for (int t = 0; t < 5; ++t) {
      int idx = lane + 64 * t;
      xiv[t] = idx < EPT ? xi[idx] : 0.f;
      xjv[t] = idx < EPT ? xj[idx] : 0.f;
    }
    float accv = 0.f;
#pragma unroll
    for (int h = 0; h < H_DIM; ++h) {
      float ph = 0.f;
#pragma unroll
      for (int t = 0; t < 5; ++t) {
        int idx = lane + 64 * t;
        if (idx < EPT) ph += xiv[t] * xjv[t] * w4[h * EPT + idx];
      }
      float invn = 1.f / (norms[i * H_DIM + h] * norms[j * H_DIM + h]);
      accv += ph * invn;
    }
#pragma unroll
    for (int o = 32; o >= 1; o >>= 1) accv += __shfl_xor(accv, o, 64);
    if (lane == 0) S[e] = accv * (1.f / 16.f);
  }
}

// ---------------- 4) thresholded row softmax -> bf16 adj ----------------
__global__ void softmax_kernel(const float* __restrict__ S, __hip_bfloat16* __restrict__ adj) {
  __shared__ float red[4];
  const int row = blockIdx.x;
  const float* s = S + (size_t)row * L_DIM;
  const int tid = threadIdx.x;
  float m = -1e30f;
  for (int j = tid; j < L_DIM; j += 256) {
    float v = s[j];
    if (v >= 0.1f && v > m) m = v;
  }
#pragma unroll
  for (int o = 32; o >= 1; o >>= 1) m = fmaxf(m, __shfl_xor(m, o, 64));
  if ((tid & 63) == 0) red[tid >> 6] = m;
  __syncthreads();
  m = fmaxf(fmaxf(red[0], red[1]), fmaxf(red[2], red[3]));
  float sum = 0.f;
  for (int j = tid; j < L_DIM; j += 256) {
    float v = s[j];
    if (v >= 0.1f) sum += __expf(v - m);
  }
#pragma unroll
  for (int o = 32; o >= 1; o >>= 1) sum += __shfl_xor(sum, o, 64);
  __syncthreads();
  if ((tid & 63) == 0) red[tid >> 6] = sum;
  __syncthreads();
  sum = red[0] + red[1] + red[2] + red[3];
  float inv = 1.f / sum;
  for (int j = tid; j < L_DIM; j += 256) {
    float v = s[j];
    float a = (v >= 0.1f) ? __expf(v - m) * inv : 0.f;
    adj[(size_t)row * L_DIM + j] = __float2bfloat16(a);
  }
}

// ---------------- helpers ----------------
__global__ void cast_bf16_kernel(const float* __restrict__ in, __hip_bfloat16* __restrict__ out,
                                 int n) {
  int i = blockIdx.x * 256 + threadIdx.x;
  if (i < n) out[i] = __float2bfloat16(in[i]);
}

template <typename T>
__global__ void transpose_bf16_kernel(const T* __restrict__ in, __hip_bfloat16* __restrict__ out,
                                      int R, int C) {
  __shared__ float tile[32][33];
  int c0 = blockIdx.x * 32, r0 = blockIdx.y * 32;
  int tx = threadIdx.x, ty = threadIdx.y;
  for (int i = ty; i < 32; i += 8) tile[i][tx] = (float)in[(size_t)(r0 + i) * C + c0 + tx];
  __syncthreads();
  for (int i = ty; i < 32; i += 8)
    out[(size_t)(c0 + i) * R + r0 + tx] = __float2bfloat16(tile[tx][i]);
}

extern "C" void kernel_launch(void* const* d_in, const int* in_sizes, int n_in, void* d_out,
                              int out_size, void* d_ws, size_t ws_size, hipStream_t stream) {
  const float* label = (const float*)d_in[0];  // [2048,512]
  const float* xpt = (const float*)d_in[1];    // [2048,300]
  const float* Wpt = (const float*)d_in[2];    // [16,300]
  const float* W0 = (const float*)d_in[3];     // [512,512]
  const float* W1 = (const float*)d_in[4];     // [512,512]
  float* out = (float*)d_out;                  // [2048,512]

  char* ws = (char*)d_ws;
  __hip_bfloat16* Y = (__hip_bfloat16*)ws;              // [0, 19,660,800)
  float* S = (float*)(ws + 19660800);                   // 16,777,216 B
  float* norms = (float*)(ws + 36438016);               // 131,072 B
  float* w4 = (float*)(ws + 36569088);                  // 19,200 B
  // borderline list lives in the Y region ABOVE adj's 8.39 MB (Y dead after gram,
  // adj only uses [0, 8388608))
  int* bl_count = (int*)(ws + 9437184);
  int* bl_list = (int*)(ws + 9437696);                  // cap 2.5M ints, ends < 19.66MB
  __hip_bfloat16* adj = (__hip_bfloat16*)ws;            // reuses Y region
  char* tmp = ws + 19660800;                            // reuses S region after softmax
  __hip_bfloat16* Lbf = (__hip_bfloat16*)tmp;
  __hip_bfloat16* W0t = (__hip_bfloat16*)(tmp + 2097152);
  __hip_bfloat16* W1t = (__hip_bfloat16*)(tmp + 2621440);
  __hip_bfloat16* T0 = (__hip_bfloat16*)(tmp + 3145728);
  __hip_bfloat16* T0t = (__hip_bfloat16*)(tmp + 5242880);
  __hip_bfloat16* X1 = (__hip_bfloat16*)(tmp + 7340032);
  __hip_bfloat16* T1 = (__hip_bfloat16*)(tmp + 9437184);
  __hip_bfloat16* T1t = (__hip_bfloat16*)(tmp + 11534336);

  compute_y_kernel<<<8192, 256, 0, stream>>>(xpt, Wpt, Y, norms);
  w4_kernel<<<19, 256, 0, stream>>>(Wpt, w4);
  // S = Y Y^T  [2048,2048], symmetric (upper blocks + mirror)
  gemm_bt<false, false, true><<<dim3(16, 16), 256, 0, stream>>>(Y, Y, S, 2048, 2048, KDIM);
  // borderline: compact then repair (load-balanced)
  hipMemsetAsync(bl_count, 0, 4, stream);
  scan_borderline<<<2048, 256, 0, stream>>>(S, bl_count, bl_list);
  repair_borderline<<<2048, 256, 0, stream>>>(S, bl_count, bl_list, xpt, w4, norms);
  softmax_kernel<<<2048, 256, 0, stream>>>(S, adj);  // adj overwrites Y region (Y dead)
  // GCN prep (runs after softmax: writes into S region)
  cast_bf16_kernel<<<4096, 256, 0, stream>>>(label, Lbf, 2048 * 512);
  transpose_bf16_kernel<float><<<dim3(16, 16), dim3(32, 8), 0, stream>>>(W0, W0t, 512, 512);
  transpose_bf16_kernel<float><<<dim3(16, 16), dim3(32, 8), 0, stream>>>(W1, W1t, 512, 512);
  // T0 = label @ W0
  gemm_bt<false, true, false><<<dim3(4, 16), 256, 0, stream>>>(Lbf, W0t, T0, 2048, 512, 512);
  transpose_bf16_kernel<__hip_bfloat16><<<dim3(16, 64), dim3(32, 8), 0, stream>>>(T0, T0t, 2048, 512);
  // X1 = relu(adj @ T0)
  gemm_bt<true, true, false><<<dim3(4, 16), 256, 0, stream>>>(adj, T0t, X1, 2048, 512, 2048);
  // T1 = X1 @ W1
  gemm_bt<false, true, false><<<dim3(4, 16), 256, 0, stream>>>(X1, W1t, T1, 2048, 512, 512);
  transpose_bf16_kernel<__hip_bfloat16><<<dim3(16, 64), dim3(32, 8), 0, stream>>>(T1, T1t, 2048, 512);
  // out = relu(adj @ T1)
  gemm_bt<true, false, false><<<dim3(4, 16), 256, 0, stream>>>(adj, T1t, out, 2048, 512, 2048);
}

// Round 4
// 345.837 us; speedup vs baseline: 1.9551x; 1.2368x over previous
//
#include <hip/hip_runtime.h>
#include <hip/hip_bf16.h>

// L=2048, E=512, E_PT=300, H=16. All inputs f32. Output f32 [2048,512].
//
// Pipeline:
//  1) Y[i, h*300+e] = (x_i*w2_h)/(max(||x_i*w2_h||,eps)*sqrt(16))  -> bf16 [2048,4800]
//  2) S = Y Y^T, symmetric: 128x64 tiles, skip fully-below-diagonal blocks, mirror-store
//  3) borderline repair: per-block LDS-compacted scan of |S-0.1|<1.5e-3, then
//     load-balanced exact-f32 recompute over the compacted list
//  4) row softmax with >=0.1 mask -> adj bf16
//  5) GCN with 64x64-tile gemms (256 blocks each for CU coverage)
//
// R4 changes: XOR-swizzled LDS (kills 16-way frag-read conflicts, was 7.8M cyc),
// double-buffered K-loop (single barrier/iter), tile shapes chosen for occupancy
// (R3 gram ran at 0.53 waves/SIMD).

typedef __attribute__((ext_vector_type(8))) short bf16x8;
typedef __attribute__((ext_vector_type(4))) float f32x4;

#define L_DIM 2048
#define EPT 300
#define H_DIM 16
#define KDIM 4800
#define WINDOW 1.5e-3f
#define LIST_CAP 2500000

// ---------------- 1) Y + norms ----------------
__global__ void compute_y_kernel(const float* __restrict__ xpt,
                                 const float* __restrict__ Wpt,
                                 __hip_bfloat16* __restrict__ Y,
                                 float* __restrict__ norms) {
  int gw = (blockIdx.x * 256 + threadIdx.x) >> 6;  // wave id = (i,h) pair
  int lane = threadIdx.x & 63;
  int i = gw >> 4, h = gw & 15;
  const float* x = xpt + i * EPT;
  const float* w = Wpt + h * EPT;
  float v[5];
  float ss = 0.f;
#pragma unroll
  for (int t = 0; t < 5; ++t) {
    int e = lane + 64 * t;
    float val = 0.f;
    if (e < EPT) {
      float we = w[e];
      val = x[e] * we * we;
    }
    v[t] = val;
    ss += val * val;
  }
#pragma unroll
  for (int o = 32; o >= 1; o >>= 1) ss += __shfl_xor(ss, o, 64);
  float n = fmaxf(sqrtf(ss), 1e-12f);
  if (lane == 0) norms[i * H_DIM + h] = n;
  float scale = 0.25f / n;  // 1/(norm*sqrt(H))
#pragma unroll
  for (int t = 0; t < 5; ++t) {
    int e = lane + 64 * t;
    if (e < EPT) Y[(size_t)i * KDIM + h * EPT + e] = __float2bfloat16(v[t] * scale);
  }
}

__global__ void w4_kernel(const float* __restrict__ Wpt, float* __restrict__ w4) {
  int i = blockIdx.x * 256 + threadIdx.x;
  if (i < H_DIM * EPT) {
    float w = Wpt[i];
    float w2 = w * w;
    w4[i] = w2 * w2;
  }
}

// ---------------- 2) bt-GEMM: C = A * B^T ----------------
// A: [M,K] bf16 rm, B: [N,K] bf16 rm. BM in {64,128}, BN=64 lane partition:
// 4 waves as (BM/64) x (4/(BM/64)); each wave 64 rows x (16*NC) cols.
// XOR-swizzled LDS: chunk c of row r stored at slot c^(r&7). Double-buffered.
template <int BM, int BN, bool RELU, bool OUT_BF16, bool MIRROR>
__global__ __launch_bounds__(256) void gemm_bt(const __hip_bfloat16* __restrict__ A,
                                               const __hip_bfloat16* __restrict__ B,
                                               void* __restrict__ Cv, int M, int N, int K) {
  constexpr int WMG = BM / 64;        // wave groups along M (1 or 2)
  constexpr int WNG = 4 / WMG;        // wave groups along N
  constexpr int NC = BN / (16 * WNG); // 16-col frags per wave
  const int row0 = blockIdx.y * BM, col0 = blockIdx.x * BN;
  if (MIRROR && col0 + BN <= row0) return;  // fully below diagonal
  __shared__ __attribute__((aligned(16))) __hip_bfloat16 As[2][BM * 64];
  __shared__ __attribute__((aligned(16))) __hip_bfloat16 Bs[2][BN * 64];
  const int tid = threadIdx.x;
  const int lane = tid & 63;
  const int wave = tid >> 6;
  const int wm = wave / WNG, wn = wave % WNG;
  const int r = lane & 15, q = lane >> 4;
  const int srow = tid >> 3;                       // staging row within 32-row group
  const int schunk = (tid & 7) ^ (srow & 7);       // swizzled source chunk

  f32x4 acc[4][NC];
#pragma unroll
  for (int a = 0; a < 4; ++a)
#pragma unroll
    for (int b = 0; b < NC; ++b) {
      f32x4 z = {0.f, 0.f, 0.f, 0.f};
      acc[a][b] = z;
    }

  const int niter = K >> 6;

#define STAGE(bufi, k0)                                                                       \
  {                                                                                           \
    _Pragma("unroll") for (int it = 0; it < BM / 32; ++it) {                                  \
      __builtin_amdgcn_global_load_lds(                                                       \
          (const __attribute__((address_space(1))) void*)(A + (size_t)(row0 + it * 32 + srow) * K + \
                                                          (k0) + schunk * 8),                 \
          (__attribute__((address_space(3))) void*)(&As[bufi][(it * 256 + tid) * 8]), 16, 0, 0); \
    }                                                                                         \
    _Pragma("unroll") for (int it = 0; it < BN / 32; ++it) {                                  \
      __builtin_amdgcn_global_load_lds(                                                       \
          (const __attribute__((address_space(1))) void*)(B + (size_t)(col0 + it * 32 + srow) * K + \
                                                          (k0) + schunk * 8),                 \
          (__attribute__((address_space(3))) void*)(&Bs[bufi][(it * 256 + tid) * 8]), 16, 0, 0); \
    }                                                                                         \
  }

  STAGE(0, 0)
  for (int k = 0; k < niter; ++k) {
    __syncthreads();  // drains stage(k) (vmcnt0) + all reads of buf (k+1)&1
    if (k + 1 < niter) STAGE((k + 1) & 1, (k + 1) << 6)
    const __hip_bfloat16* as = As[k & 1];
    const __hip_bfloat16* bs = Bs[k & 1];
#pragma unroll
    for (int kk = 0; kk < 2; ++kk) {
      const int ch = ((kk * 4 + q) ^ (r & 7)) * 8;  // swizzled read chunk
      bf16x8 af[4], bfr[NC];
#pragma unroll
      for (int t = 0; t < 4; ++t)
        af[t] = *(const bf16x8*)(as + (wm * 64 + t * 16 + r) * 64 + ch);
#pragma unroll
      for (int c = 0; c < NC; ++c)
        bfr[c] = *(const bf16x8*)(bs + (wn * 16 * NC + c * 16 + r) * 64 + ch);
#pragma unroll
      for (int tm = 0; tm < 4; ++tm)
#pragma unroll
        for (int tn = 0; tn < NC; ++tn)
          acc[tm][tn] = __builtin_amdgcn_mfma_f32_16x16x32_bf16(af[tm], bfr[tn], acc[tm][tn], 0, 0, 0);
    }
  }
#undef STAGE
  // C/D layout: col = lane&15, row = (lane>>4)*4 + reg   [guide §3, m89-verified]
#pragma unroll
  for (int tm = 0; tm < 4; ++tm) {
    int gr0 = row0 + wm * 64 + tm * 16 + q * 4;
#pragma unroll
    for (int tn = 0; tn < NC; ++tn) {
      int gc = col0 + wn * 16 * NC + tn * 16 + r;
#pragma unroll
      for (int p = 0; p < 4; ++p) {
        float vv = acc[tm][tn][p];
        if (RELU) vv = fmaxf(vv, 0.f);
        if (OUT_BF16)
          ((__hip_bfloat16*)Cv)[(size_t)(gr0 + p) * N + gc] = __float2bfloat16(vv);
        else {
          ((float*)Cv)[(size_t)(gr0 + p) * N + gc] = vv;
          if (MIRROR && gc > gr0 + p) ((float*)Cv)[(size_t)gc * N + (gr0 + p)] = vv;
        }
      }
    }
  }
}

// ---------------- 3a) scan: per-block LDS compaction, 1 global atomic/block ----
__global__ __launch_bounds__(256) void scan_borderline(const float* __restrict__ S,
                                                       int* __restrict__ count,
                                                       int* __restrict__ list) {
  __shared__ int lqueue[2048];
  __shared__ int lcount;
  __shared__ int gbase;
  if (threadIdx.x == 0) lcount = 0;
  __syncthreads();
  const int base_idx = blockIdx.x * 2048;
#pragma unroll
  for (int t = 0; t < 2; ++t) {
    int idx = base_idx + t * 1024 + threadIdx.x * 4;
    float4 v = *(const float4*)(S + idx);
    float vv[4] = {v.x, v.y, v.z, v.w};
#pragma unroll
    for (int u = 0; u < 4; ++u) {
      if (fabsf(vv[u] - 0.1f) < WINDOW) {
        int p = atomicAdd(&lcount, 1);  // LDS atomic — cheap
        lqueue[p] = idx + u;
      }
    }
  }
  __syncthreads();
  if (threadIdx.x == 0) gbase = atomicAdd(count, lcount);
  __syncthreads();
  int n = lcount, g0 = gbase;
  for (int k = threadIdx.x; k < n; k += 256) {
    int pos = g0 + k;
    if (pos < LIST_CAP) list[pos] = lqueue[k];
  }
}

// ---------------- 3b) exact f32 repair over compacted list ----------------
__global__ void repair_borderline(float* __restrict__ S, const int* __restrict__ count,
                                  const int* __restrict__ list, const float* __restrict__ xpt,
                                  const float* __restrict__ w4, const float* __restrict__ norms) {
  const int lane = threadIdx.x & 63;
  const int wid = (blockIdx.x * 256 + threadIdx.x) >> 6;
  const int nw = gridDim.x * 4;
  int n = *count;
  if (n > LIST_CAP) n = LIST_CAP;
  for (int k = wid; k < n; k += nw) {
    int e = list[k];
    int i = e >> 11, j = e & 2047;
    const float* xi = xpt + i * EPT;
    const float* xj = xpt + j * EPT;
    float xiv[5], xjv[5];
#pragma unroll
    for (int t = 0; t < 5; ++t) {
      int idx = lane + 64 * t;
      xiv[t] = idx < EPT ? xi[idx] : 0.f;
      xjv[t] = idx < EPT ? xj[idx] : 0.f;
    }
    float accv = 0.f;
#pragma unroll
    for (int h = 0; h < H_DIM; ++h) {
      float ph = 0.f;
#pragma unroll
      for (int t = 0; t < 5; ++t) {
        int idx = lane + 64 * t;
        if (idx < EPT) ph += xiv[t] * xjv[t] * w4[h * EPT + idx];
      }
      float invn = 1.f / (norms[i * H_DIM + h] * norms[j * H_DIM + h]);
      accv += ph * invn;
    }
#pragma unroll
    for (int o = 32; o >= 1; o >>= 1) accv += __shfl_xor(accv, o, 64);
    if (lane == 0) S[e] = accv * (1.f / 16.f);
  }
}

// ---------------- 4) thresholded row softmax -> bf16 adj ----------------
__global__ void softmax_kernel(const float* __restrict__ S, __hip_bfloat16* __restrict__ adj) {
  __shared__ float red[4];
  const int row = blockIdx.x;
  const float* s = S + (size_t)row * L_DIM;
  const int tid = threadIdx.x;
  float m = -1e30f;
  for (int j = tid; j < L_DIM; j += 256) {
    float v = s[j];
    if (v >= 0.1f && v > m) m = v;
  }
#pragma unroll
  for (int o = 32; o >= 1; o >>= 1) m = fmaxf(m, __shfl_xor(m, o, 64));
  if ((tid & 63) == 0) red[tid >> 6] = m;
  __syncthreads();
  m = fmaxf(fmaxf(red[0], red[1]), fmaxf(red[2], red[3]));
  float sum = 0.f;
  for (int j = tid; j < L_DIM; j += 256) {
    float v = s[j];
    if (v >= 0.1f) sum += __expf(v - m);
  }
#pragma unroll
  for (int o = 32; o >= 1; o >>= 1) sum += __shfl_xor(sum, o, 64);
  __syncthreads();
  if ((tid & 63) == 0) red[tid >> 6] = sum;
  __syncthreads();
  sum = red[0] + red[1] + red[2] + red[3];
  float inv = 1.f / sum;
  for (int j = tid; j < L_DIM; j += 256) {
    float v = s[j];
    float a = (v >= 0.1f) ? __expf(v - m) * inv : 0.f;
    adj[(size_t)row * L_DIM + j] = __float2bfloat16(a);
  }
}

// ---------------- helpers ----------------
__global__ void cast_bf16_kernel(const float* __restrict__ in, __hip_bfloat16* __restrict__ out,
                                 int n) {
  int i = blockIdx.x * 256 + threadIdx.x;
  if (i < n) out[i] = __float2bfloat16(in[i]);
}

template <typename T>
__global__ void transpose_bf16_kernel(const T* __restrict__ in, __hip_bfloat16* __restrict__ out,
                                      int R, int C) {
  __shared__ float tile[32][33];
  int c0 = blockIdx.x * 32, r0 = blockIdx.y * 32;
  int tx = threadIdx.x, ty = threadIdx.y;
  for (int i = ty; i < 32; i += 8) tile[i][tx] = (float)in[(size_t)(r0 + i) * C + c0 + tx];
  __syncthreads();
  for (int i = ty; i < 32; i += 8)
    out[(size_t)(c0 + i) * R + r0 + tx] = __float2bfloat16(tile[tx][i]);
}

extern "C" void kernel_launch(void* const* d_in, const int* in_sizes, int n_in, void* d_out,
                              int out_size, void* d_ws, size_t ws_size, hipStream_t stream) {
  const float* label = (const float*)d_in[0];  // [2048,512]
  const float* xpt = (const float*)d_in[1];    // [2048,300]
  const float* Wpt = (const float*)d_in[2];    // [16,300]
  const float* W0 = (const float*)d_in[3];     // [512,512]
  const float* W1 = (const float*)d_in[4];     // [512,512]
  float* out = (float*)d_out;                  // [2048,512]

  char* ws = (char*)d_ws;
  __hip_bfloat16* Y = (__hip_bfloat16*)ws;              // [0, 19,660,800)
  float* S = (float*)(ws + 19660800);                   // 16,777,216 B
  float* norms = (float*)(ws + 36438016);               // 131,072 B
  float* w4 = (float*)(ws + 36569088);                  // 19,200 B
  int* bl_count = (int*)(ws + 9437184);                 // in Y region above adj's 8.39MB
  int* bl_list = (int*)(ws + 9437696);                  // cap 2.5M ints, ends < 19.66MB
  __hip_bfloat16* adj = (__hip_bfloat16*)ws;            // reuses Y region
  char* tmp = ws + 19660800;                            // reuses S region after softmax
  __hip_bfloat16* Lbf = (__hip_bfloat16*)tmp;
  __hip_bfloat16* W0t = (__hip_bfloat16*)(tmp + 2097152);
  __hip_bfloat16* W1t = (__hip_bfloat16*)(tmp + 2621440);
  __hip_bfloat16* T0 = (__hip_bfloat16*)(tmp + 3145728);
  __hip_bfloat16* T0t = (__hip_bfloat16*)(tmp + 5242880);
  __hip_bfloat16* X1 = (__hip_bfloat16*)(tmp + 7340032);
  __hip_bfloat16* T1 = (__hip_bfloat16*)(tmp + 9437184);
  __hip_bfloat16* T1t = (__hip_bfloat16*)(tmp + 11534336);

  compute_y_kernel<<<8192, 256, 0, stream>>>(xpt, Wpt, Y, norms);
  w4_kernel<<<19, 256, 0, stream>>>(Wpt, w4);
  // S = Y Y^T  [2048,2048], symmetric: 128x64 tiles, 272 active blocks + mirror
  gemm_bt<128, 64, false, false, true><<<dim3(32, 16), 256, 0, stream>>>(Y, Y, S, 2048, 2048, KDIM);
  // borderline: compact then repair (load-balanced)
  hipMemsetAsync(bl_count, 0, 4, stream);
  scan_borderline<<<2048, 256, 0, stream>>>(S, bl_count, bl_list);
  repair_borderline<<<2048, 256, 0, stream>>>(S, bl_count, bl_list, xpt, w4, norms);
  softmax_kernel<<<2048, 256, 0, stream>>>(S, adj);  // adj overwrites Y region (Y dead)
  // GCN prep (runs after softmax: writes into S region)
  cast_bf16_kernel<<<4096, 256, 0, stream>>>(label, Lbf, 2048 * 512);
  transpose_bf16_kernel<float><<<dim3(16, 16), dim3(32, 8), 0, stream>>>(W0, W0t, 512, 512);
  transpose_bf16_kernel<float><<<dim3(16, 16), dim3(32, 8), 0, stream>>>(W1, W1t, 512, 512);
  // T0 = label @ W0   (2048x512, K=512) — 64x64 tiles: 256 blocks
  gemm_bt<64, 64, false, true, false><<<dim3(8, 32), 256, 0, stream>>>(Lbf, W0t, T0, 2048, 512, 512);
  transpose_bf16_kernel<__hip_bfloat16><<<dim3(16, 64), dim3(32, 8), 0, stream>>>(T0, T0t, 2048, 512);
  // X1 = relu(adj @ T0)  (K=2048)
  gemm_bt<64, 64, true, true, false><<<dim3(8, 32), 256, 0, stream>>>(adj, T0t, X1, 2048, 512, 2048);
  // T1 = X1 @ W1
  gemm_bt<64, 64, false, true, false><<<dim3(8, 32), 256, 0, stream>>>(X1, W1t, T1, 2048, 512, 512);
  transpose_bf16_kernel<__hip_bfloat16><<<dim3(16, 64), dim3(32, 8), 0, stream>>>(T1, T1t, 2048, 512);
  // out = relu(adj @ T1)
  gemm_bt<64, 64, true, false, false><<<dim3(8, 32), 256, 0, stream>>>(adj, T1t, out, 2048, 512, 2048);
}

// Round 5
// 323.165 us; speedup vs baseline: 2.0922x; 1.0702x over previous
//
#include <hip/hip_runtime.h>
#include <hip/hip_bf16.h>

// L=2048, E=512, E_PT=300, H=16. All inputs f32. Output f32 [2048,512].
//
// Pipeline:
//  1) Y[i, h*300+e] = (x_i*w2_h)/(max(||x_i*w2_h||,eps)*sqrt(16))  -> bf16 [2048,4800]
//  2) S = Y Y^T, symmetric: 128x64 tiles, skip fully-below-diagonal blocks, mirror-store
//  3) borderline repair: scan UPPER TRIANGLE only (S bit-exact symmetric),
//     per-block LDS compaction; repair over contiguous per-wave chunks
//     (list is i-major -> xi register/L2 reuse), write both S[ij] and S[ji].
//     R4's strided list-walk re-fetched xi/xj cold per entry (120MB FETCH).
//  4) row softmax with >=0.1 mask -> adj bf16
//  5) GCN with 64x64-tile gemms (256 blocks each for CU coverage)

typedef __attribute__((ext_vector_type(8))) short bf16x8;
typedef __attribute__((ext_vector_type(4))) float f32x4;

#define L_DIM 2048
#define EPT 300
#define H_DIM 16
#define KDIM 4800
#define WINDOW 1.5e-3f
#define LIST_CAP 2500000

// ---------------- 1) Y + norms ----------------
__global__ void compute_y_kernel(const float* __restrict__ xpt,
                                 const float* __restrict__ Wpt,
                                 __hip_bfloat16* __restrict__ Y,
                                 float* __restrict__ norms) {
  int gw = (blockIdx.x * 256 + threadIdx.x) >> 6;  // wave id = (i,h) pair
  int lane = threadIdx.x & 63;
  int i = gw >> 4, h = gw & 15;
  const float* x = xpt + i * EPT;
  const float* w = Wpt + h * EPT;
  float v[5];
  float ss = 0.f;
#pragma unroll
  for (int t = 0; t < 5; ++t) {
    int e = lane + 64 * t;
    float val = 0.f;
    if (e < EPT) {
      float we = w[e];
      val = x[e] * we * we;
    }
    v[t] = val;
    ss += val * val;
  }
#pragma unroll
  for (int o = 32; o >= 1; o >>= 1) ss += __shfl_xor(ss, o, 64);
  float n = fmaxf(sqrtf(ss), 1e-12f);
  if (lane == 0) norms[i * H_DIM + h] = n;
  float scale = 0.25f / n;  // 1/(norm*sqrt(H))
#pragma unroll
  for (int t = 0; t < 5; ++t) {
    int e = lane + 64 * t;
    if (e < EPT) Y[(size_t)i * KDIM + h * EPT + e] = __float2bfloat16(v[t] * scale);
  }
}

__global__ void w4_kernel(const float* __restrict__ Wpt, float* __restrict__ w4) {
  int i = blockIdx.x * 256 + threadIdx.x;
  if (i < H_DIM * EPT) {
    float w = Wpt[i];
    float w2 = w * w;
    w4[i] = w2 * w2;
  }
}

// ---------------- 2) bt-GEMM: C = A * B^T ----------------
// A: [M,K] bf16 rm, B: [N,K] bf16 rm. BM in {64,128}, BN=64 lane partition:
// 4 waves as (BM/64) x (4/(BM/64)); each wave 64 rows x (16*NC) cols.
// XOR-swizzled LDS: chunk c of row r stored at slot c^(r&7). Double-buffered.
template <int BM, int BN, bool RELU, bool OUT_BF16, bool MIRROR>
__global__ __launch_bounds__(256) void gemm_bt(const __hip_bfloat16* __restrict__ A,
                                               const __hip_bfloat16* __restrict__ B,
                                               void* __restrict__ Cv, int M, int N, int K) {
  constexpr int WMG = BM / 64;        // wave groups along M (1 or 2)
  constexpr int WNG = 4 / WMG;        // wave groups along N
  constexpr int NC = BN / (16 * WNG); // 16-col frags per wave
  const int row0 = blockIdx.y * BM, col0 = blockIdx.x * BN;
  if (MIRROR && col0 + BN <= row0) return;  // fully below diagonal
  __shared__ __attribute__((aligned(16))) __hip_bfloat16 As[2][BM * 64];
  __shared__ __attribute__((aligned(16))) __hip_bfloat16 Bs[2][BN * 64];
  const int tid = threadIdx.x;
  const int lane = tid & 63;
  const int wave = tid >> 6;
  const int wm = wave / WNG, wn = wave % WNG;
  const int r = lane & 15, q = lane >> 4;
  const int srow = tid >> 3;                       // staging row within 32-row group
  const int schunk = (tid & 7) ^ (srow & 7);       // swizzled source chunk

  f32x4 acc[4][NC];
#pragma unroll
  for (int a = 0; a < 4; ++a)
#pragma unroll
    for (int b = 0; b < NC; ++b) {
      f32x4 z = {0.f, 0.f, 0.f, 0.f};
      acc[a][b] = z;
    }

  const int niter = K >> 6;

#define STAGE(bufi, k0)                                                                       \
  {                                                                                           \
    _Pragma("unroll") for (int it = 0; it < BM / 32; ++it) {                                  \
      __builtin_amdgcn_global_load_lds(                                                       \
          (const __attribute__((address_space(1))) void*)(A + (size_t)(row0 + it * 32 + srow) * K + \
                                                          (k0) + schunk * 8),                 \
          (__attribute__((address_space(3))) void*)(&As[bufi][(it * 256 + tid) * 8]), 16, 0, 0); \
    }                                                                                         \
    _Pragma("unroll") for (int it = 0; it < BN / 32; ++it) {                                  \
      __builtin_amdgcn_global_load_lds(                                                       \
          (const __attribute__((address_space(1))) void*)(B + (size_t)(col0 + it * 32 + srow) * K + \
                                                          (k0) + schunk * 8),                 \
          (__attribute__((address_space(3))) void*)(&Bs[bufi][(it * 256 + tid) * 8]), 16, 0, 0); \
    }                                                                                         \
  }

  STAGE(0, 0)
  for (int k = 0; k < niter; ++k) {
    __syncthreads();  // drains stage(k) (vmcnt0) + all reads of buf (k+1)&1
    if (k + 1 < niter) STAGE((k + 1) & 1, (k + 1) << 6)
    const __hip_bfloat16* as = As[k & 1];
    const __hip_bfloat16* bs = Bs[k & 1];
#pragma unroll
    for (int kk = 0; kk < 2; ++kk) {
      const int ch = ((kk * 4 + q) ^ (r & 7)) * 8;  // swizzled read chunk
      bf16x8 af[4], bfr[NC];
#pragma unroll
      for (int t = 0; t < 4; ++t)
        af[t] = *(const bf16x8*)(as + (wm * 64 + t * 16 + r) * 64 + ch);
#pragma unroll
      for (int c = 0; c < NC; ++c)
        bfr[c] = *(const bf16x8*)(bs + (wn * 16 * NC + c * 16 + r) * 64 + ch);
#pragma unroll
      for (int tm = 0; tm < 4; ++tm)
#pragma unroll
        for (int tn = 0; tn < NC; ++tn)
          acc[tm][tn] = __builtin_amdgcn_mfma_f32_16x16x32_bf16(af[tm], bfr[tn], acc[tm][tn], 0, 0, 0);
    }
  }
#undef STAGE
  // C/D layout: col = lane&15, row = (lane>>4)*4 + reg   [guide §3, m89-verified]
#pragma unroll
  for (int tm = 0; tm < 4; ++tm) {
    int gr0 = row0 + wm * 64 + tm * 16 + q * 4;
#pragma unroll
    for (int tn = 0; tn < NC; ++tn) {
      int gc = col0 + wn * 16 * NC + tn * 16 + r;
#pragma unroll
      for (int p = 0; p < 4; ++p) {
        float vv = acc[tm][tn][p];
        if (RELU) vv = fmaxf(vv, 0.f);
        if (OUT_BF16)
          ((__hip_bfloat16*)Cv)[(size_t)(gr0 + p) * N + gc] = __float2bfloat16(vv);
        else {
          ((float*)Cv)[(size_t)(gr0 + p) * N + gc] = vv;
          if (MIRROR && gc > gr0 + p) ((float*)Cv)[(size_t)gc * N + (gr0 + p)] = vv;
        }
      }
    }
  }
}

// ---------------- 3a) scan upper triangle, per-block LDS compaction ----------
// Block = one row i; push only j >= i (S is bit-exact symmetric).
__global__ __launch_bounds__(256) void scan_borderline(const float* __restrict__ S,
                                                       int* __restrict__ count,
                                                       int* __restrict__ list) {
  __shared__ int lqueue[2048];
  __shared__ int lcount;
  __shared__ int gbase;
  if (threadIdx.x == 0) lcount = 0;
  __syncthreads();
  const int row = blockIdx.x;
  const int base_idx = row * 2048;
#pragma unroll
  for (int t = 0; t < 2; ++t) {
    int idx = base_idx + t * 1024 + threadIdx.x * 4;
    float4 v = *(const float4*)(S + idx);
    float vv[4] = {v.x, v.y, v.z, v.w};
#pragma unroll
    for (int u = 0; u < 4; ++u) {
      int j = (idx + u) & 2047;
      if (j >= row && fabsf(vv[u] - 0.1f) < WINDOW) {
        int p = atomicAdd(&lcount, 1);  // LDS atomic — cheap
        lqueue[p] = idx + u;
      }
    }
  }
  __syncthreads();
  if (threadIdx.x == 0) gbase = atomicAdd(count, lcount);
  __syncthreads();
  int n = lcount, g0 = gbase;
  for (int k = threadIdx.x; k < n; k += 256) {
    int pos = g0 + k;
    if (pos < LIST_CAP) list[pos] = lqueue[k];
  }
}

// ---------------- 3b) exact f32 repair, contiguous chunks, mirror write -----
__global__ void repair_borderline(float* __restrict__ S, const int* __restrict__ count,
                                  const int* __restrict__ list, const float* __restrict__ xpt,
                                  const float* __restrict__ w4, const float* __restrict__ norms) {
  const int lane = threadIdx.x & 63;
  const int wid = (blockIdx.x * 256 + threadIdx.x) >> 6;
  const int nw = gridDim.x * 4;
  int n = *count;
  if (n > LIST_CAP) n = LIST_CAP;
  const int chunk = (n + nw - 1) / nw;
  int k0 = wid * chunk;
  int k1 = k0 + chunk < n ? k0 + chunk : n;
  int cur_i = -1;
  float xiv[5];
  for (int k = k0; k < k1; ++k) {
    int e = list[k];
    int i = e >> 11, j = e & 2047;
    if (i != cur_i) {  // list is i-major: xi reused across same-i runs
      const float* xi = xpt + i * EPT;
#pragma unroll
      for (int t = 0; t < 5; ++t) {
        int idx = lane + 64 * t;
        xiv[t] = idx < EPT ? xi[idx] : 0.f;
      }
      cur_i = i;
    }
    const float* xj = xpt + j * EPT;
    float xjv[5];
#pragma unroll
    for (int t = 0; t < 5; ++t) {
      int idx = lane + 64 * t;
      xjv[t] = idx < EPT ? xj[idx] : 0.f;
    }
    float accv = 0.f;
#pragma unroll
    for (int h = 0; h < H_DIM; ++h) {
      float ph = 0.f;
#pragma unroll
      for (int t = 0; t < 5; ++t) {
        int idx = lane + 64 * t;
        if (idx < EPT) ph += xiv[t] * xjv[t] * w4[h * EPT + idx];
      }
      float invn = 1.f / (norms[i * H_DIM + h] * norms[j * H_DIM + h]);
      accv += ph * invn;
    }
#pragma unroll
    for (int o = 32; o >= 1; o >>= 1) accv += __shfl_xor(accv, o, 64);
    if (lane == 0) {
      float val = accv * (1.f / 16.f);
      S[(size_t)i * L_DIM + j] = val;
      S[(size_t)j * L_DIM + i] = val;  // symmetric twin
    }
  }
}

// ---------------- 4) thresholded row softmax -> bf16 adj ----------------
__global__ void softmax_kernel(const float* __restrict__ S, __hip_bfloat16* __restrict__ adj) {
  __shared__ float red[4];
  const int row = blockIdx.x;
  const float* s = S + (size_t)row * L_DIM;
  const int tid = threadIdx.x;
  float m = -1e30f;
  for (int j = tid; j < L_DIM; j += 256) {
    float v = s[j];
    if (v >= 0.1f && v > m) m = v;
  }
#pragma unroll
  for (int o = 32; o >= 1; o >>= 1) m = fmaxf(m, __shfl_xor(m, o, 64));
  if ((tid & 63) == 0) red[tid >> 6] = m;
  __syncthreads();
  m = fmaxf(fmaxf(red[0], red[1]), fmaxf(red[2], red[3]));
  float sum = 0.f;
  for (int j = tid; j < L_DIM; j += 256) {
    float v = s[j];
    if (v >= 0.1f) sum += __expf(v - m);
  }
#pragma unroll
  for (int o = 32; o >= 1; o >>= 1) sum += __shfl_xor(sum, o, 64);
  __syncthreads();
  if ((tid & 63) == 0) red[tid >> 6] = sum;
  __syncthreads();
  sum = red[0] + red[1] + red[2] + red[3];
  float inv = 1.f / sum;
  for (int j = tid; j < L_DIM; j += 256) {
    float v = s[j];
    float a = (v >= 0.1f) ? __expf(v - m) * inv : 0.f;
    adj[(size_t)row * L_DIM + j] = __float2bfloat16(a);
  }
}

// ---------------- helpers ----------------
__global__ void cast_bf16_kernel(const float* __restrict__ in, __hip_bfloat16* __restrict__ out,
                                 int n) {
  int i = blockIdx.x * 256 + threadIdx.x;
  if (i < n) out[i] = __float2bfloat16(in[i]);
}

template <typename T>
__global__ void transpose_bf16_kernel(const T* __restrict__ in, __hip_bfloat16* __restrict__ out,
                                      int R, int C) {
  __shared__ float tile[32][33];
  int c0 = blockIdx.x * 32, r0 = blockIdx.y * 32;
  int tx = threadIdx.x, ty = threadIdx.y;
  for (int i = ty; i < 32; i += 8) tile[i][tx] = (float)in[(size_t)(r0 + i) * C + c0 + tx];
  __syncthreads();
  for (int i = ty; i < 32; i += 8)
    out[(size_t)(c0 + i) * R + r0 + tx] = __float2bfloat16(tile[tx][i]);
}

extern "C" void kernel_launch(void* const* d_in, const int* in_sizes, int n_in, void* d_out,
                              int out_size, void* d_ws, size_t ws_size, hipStream_t stream) {
  const float* label = (const float*)d_in[0];  // [2048,512]
  const float* xpt = (const float*)d_in[1];    // [2048,300]
  const float* Wpt = (const float*)d_in[2];    // [16,300]
  const float* W0 = (const float*)d_in[3];     // [512,512]
  const float* W1 = (const float*)d_in[4];     // [512,512]
  float* out = (float*)d_out;                  // [2048,512]

  char* ws = (char*)d_ws;
  __hip_bfloat16* Y = (__hip_bfloat16*)ws;              // [0, 19,660,800)
  float* S = (float*)(ws + 19660800);                   // 16,777,216 B
  float* norms = (float*)(ws + 36438016);               // 131,072 B
  float* w4 = (float*)(ws + 36569088);                  // 19,200 B
  int* bl_count = (int*)(ws + 9437184);                 // in Y region above adj's 8.39MB
  int* bl_list = (int*)(ws + 9437696);                  // cap 2.5M ints, ends < 19.66MB
  __hip_bfloat16* adj = (__hip_bfloat16*)ws;            // reuses Y region
  char* tmp = ws + 19660800;                            // reuses S region after softmax
  __hip_bfloat16* Lbf = (__hip_bfloat16*)tmp;
  __hip_bfloat16* W0t = (__hip_bfloat16*)(tmp + 2097152);
  __hip_bfloat16* W1t = (__hip_bfloat16*)(tmp + 2621440);
  __hip_bfloat16* T0 = (__hip_bfloat16*)(tmp + 3145728);
  __hip_bfloat16* T0t = (__hip_bfloat16*)(tmp + 5242880);
  __hip_bfloat16* X1 = (__hip_bfloat16*)(tmp + 7340032);
  __hip_bfloat16* T1 = (__hip_bfloat16*)(tmp + 9437184);
  __hip_bfloat16* T1t = (__hip_bfloat16*)(tmp + 11534336);

  compute_y_kernel<<<8192, 256, 0, stream>>>(xpt, Wpt, Y, norms);
  w4_kernel<<<19, 256, 0, stream>>>(Wpt, w4);
  // S = Y Y^T  [2048,2048], symmetric: 128x64 tiles, 272 active blocks + mirror
  gemm_bt<128, 64, false, false, true><<<dim3(32, 16), 256, 0, stream>>>(Y, Y, S, 2048, 2048, KDIM);
  // borderline: compact (upper-tri only) then repair (contiguous chunks, mirror write)
  hipMemsetAsync(bl_count, 0, 4, stream);
  scan_borderline<<<2048, 256, 0, stream>>>(S, bl_count, bl_list);
  repair_borderline<<<2048, 256, 0, stream>>>(S, bl_count, bl_list, xpt, w4, norms);
  softmax_kernel<<<2048, 256, 0, stream>>>(S, adj);  // adj overwrites Y region (Y dead)
  // GCN prep (runs after softmax: writes into S region)
  cast_bf16_kernel<<<4096, 256, 0, stream>>>(label, Lbf, 2048 * 512);
  transpose_bf16_kernel<float><<<dim3(16, 16), dim3(32, 8), 0, stream>>>(W0, W0t, 512, 512);
  transpose_bf16_kernel<float><<<dim3(16, 16), dim3(32, 8), 0, stream>>>(W1, W1t, 512, 512);
  // T0 = label @ W0   (2048x512, K=512) — 64x64 tiles: 256 blocks
  gemm_bt<64, 64, false, true, false><<<dim3(8, 32), 256, 0, stream>>>(Lbf, W0t, T0, 2048, 512, 512);
  transpose_bf16_kernel<__hip_bfloat16><<<dim3(16, 64), dim3(32, 8), 0, stream>>>(T0, T0t, 2048, 512);
  // X1 = relu(adj @ T0)  (K=2048)
  gemm_bt<64, 64, true, true, false><<<dim3(8, 32), 256, 0, stream>>>(adj, T0t, X1, 2048, 512, 2048);
  // T1 = X1 @ W1
  gemm_bt<64, 64, false, true, false><<<dim3(8, 32), 256, 0, stream>>>(X1, W1t, T1, 2048, 512, 512);
  transpose_bf16_kernel<__hip_bfloat16><<<dim3(16, 64), dim3(32, 8), 0, stream>>>(T1, T1t, 2048, 512);
  // out = relu(adj @ T1)
  gemm_bt<64, 64, true, false, false><<<dim3(8, 32), 256, 0, stream>>>(adj, T1t, out, 2048, 512, 2048);
}

// Round 8
// 316.167 us; speedup vs baseline: 2.1385x; 1.0221x over previous
//
#include <hip/hip_runtime.h>
#include <hip/hip_bf16.h>

// L=2048, E=512, E_PT=300, H=16. All inputs f32. Output f32 [2048,512].
//
// R8: BISECT ROUND. R6+R7 both crashed; common new code was {prep fusion,
// GCN restructure, window}. This round = R5 verbatim (proven 323us) plus ONLY
// the GCN restructure half: T0t=(label@W0)^T computed directly as W0t*Lbf^T
// (and T1t=W1t*X1^T), relu baked into adj-gemms, no transposes of T0/T1.
// No prep fusion, no split-K, WINDOW back at proven 1.5e-3.

typedef __attribute__((ext_vector_type(8))) short bf16x8;
typedef __attribute__((ext_vector_type(4))) float f32x4;

#define L_DIM 2048
#define EPT 300
#define H_DIM 16
#define KDIM 4800
#define WINDOW 1.5e-3f
#define LIST_CAP 2500000

// ---------------- 1) Y + norms ----------------
__global__ void compute_y_kernel(const float* __restrict__ xpt,
                                 const float* __restrict__ Wpt,
                                 __hip_bfloat16* __restrict__ Y,
                                 float* __restrict__ norms) {
  int gw = (blockIdx.x * 256 + threadIdx.x) >> 6;  // wave id = (i,h) pair
  int lane = threadIdx.x & 63;
  int i = gw >> 4, h = gw & 15;
  const float* x = xpt + i * EPT;
  const float* w = Wpt + h * EPT;
  float v[5];
  float ss = 0.f;
#pragma unroll
  for (int t = 0; t < 5; ++t) {
    int e = lane + 64 * t;
    float val = 0.f;
    if (e < EPT) {
      float we = w[e];
      val = x[e] * we * we;
    }
    v[t] = val;
    ss += val * val;
  }
#pragma unroll
  for (int o = 32; o >= 1; o >>= 1) ss += __shfl_xor(ss, o, 64);
  float n = fmaxf(sqrtf(ss), 1e-12f);
  if (lane == 0) norms[i * H_DIM + h] = n;
  float scale = 0.25f / n;  // 1/(norm*sqrt(H))
#pragma unroll
  for (int t = 0; t < 5; ++t) {
    int e = lane + 64 * t;
    if (e < EPT) Y[(size_t)i * KDIM + h * EPT + e] = __float2bfloat16(v[t] * scale);
  }
}

__global__ void w4_kernel(const float* __restrict__ Wpt, float* __restrict__ w4) {
  int i = blockIdx.x * 256 + threadIdx.x;
  if (i < H_DIM * EPT) {
    float w = Wpt[i];
    float w2 = w * w;
    w4[i] = w2 * w2;
  }
}

// ---------------- 2) bt-GEMM: C = A * B^T ----------------
// A: [M,K] bf16 rm, B: [N,K] bf16 rm. BM in {64,128}, BN=64 lane partition:
// 4 waves as (BM/64) x (4/(BM/64)); each wave 64 rows x (16*NC) cols.
// XOR-swizzled LDS: chunk c of row r stored at slot c^(r&7). Double-buffered.
template <int BM, int BN, bool RELU, bool OUT_BF16, bool MIRROR>
__global__ __launch_bounds__(256) void gemm_bt(const __hip_bfloat16* __restrict__ A,
                                               const __hip_bfloat16* __restrict__ B,
                                               void* __restrict__ Cv, int M, int N, int K) {
  constexpr int WMG = BM / 64;        // wave groups along M (1 or 2)
  constexpr int WNG = 4 / WMG;        // wave groups along N
  constexpr int NC = BN / (16 * WNG); // 16-col frags per wave
  const int row0 = blockIdx.y * BM, col0 = blockIdx.x * BN;
  if (MIRROR && col0 + BN <= row0) return;  // fully below diagonal
  __shared__ __attribute__((aligned(16))) __hip_bfloat16 As[2][BM * 64];
  __shared__ __attribute__((aligned(16))) __hip_bfloat16 Bs[2][BN * 64];
  const int tid = threadIdx.x;
  const int lane = tid & 63;
  const int wave = tid >> 6;
  const int wm = wave / WNG, wn = wave % WNG;
  const int r = lane & 15, q = lane >> 4;
  const int srow = tid >> 3;                       // staging row within 32-row group
  const int schunk = (tid & 7) ^ (srow & 7);       // swizzled source chunk

  f32x4 acc[4][NC];
#pragma unroll
  for (int a = 0; a < 4; ++a)
#pragma unroll
    for (int b = 0; b < NC; ++b) {
      f32x4 z = {0.f, 0.f, 0.f, 0.f};
      acc[a][b] = z;
    }

  const int niter = K >> 6;

#define STAGE(bufi, k0)                                                                       \
  {                                                                                           \
    _Pragma("unroll") for (int it = 0; it < BM / 32; ++it) {                                  \
      __builtin_amdgcn_global_load_lds(                                                       \
          (const __attribute__((address_space(1))) void*)(A + (size_t)(row0 + it * 32 + srow) * K + \
                                                          (k0) + schunk * 8),                 \
          (__attribute__((address_space(3))) void*)(&As[bufi][(it * 256 + tid) * 8]), 16, 0, 0); \
    }                                                                                         \
    _Pragma("unroll") for (int it = 0; it < BN / 32; ++it) {                                  \
      __builtin_amdgcn_global_load_lds(                                                       \
          (const __attribute__((address_space(1))) void*)(B + (size_t)(col0 + it * 32 + srow) * K + \
                                                          (k0) + schunk * 8),                 \
          (__attribute__((address_space(3))) void*)(&Bs[bufi][(it * 256 + tid) * 8]), 16, 0, 0); \
    }                                                                                         \
  }

  STAGE(0, 0)
  for (int k = 0; k < niter; ++k) {
    __syncthreads();  // drains stage(k) (vmcnt0) + all reads of buf (k+1)&1
    if (k + 1 < niter) STAGE((k + 1) & 1, (k + 1) << 6)
    const __hip_bfloat16* as = As[k & 1];
    const __hip_bfloat16* bs = Bs[k & 1];
#pragma unroll
    for (int kk = 0; kk < 2; ++kk) {
      const int ch = ((kk * 4 + q) ^ (r & 7)) * 8;  // swizzled read chunk
      bf16x8 af[4], bfr[NC];
#pragma unroll
      for (int t = 0; t < 4; ++t)
        af[t] = *(const bf16x8*)(as + (wm * 64 + t * 16 + r) * 64 + ch);
#pragma unroll
      for (int c = 0; c < NC; ++c)
        bfr[c] = *(const bf16x8*)(bs + (wn * 16 * NC + c * 16 + r) * 64 + ch);
#pragma unroll
      for (int tm = 0; tm < 4; ++tm)
#pragma unroll
        for (int tn = 0; tn < NC; ++tn)
          acc[tm][tn] = __builtin_amdgcn_mfma_f32_16x16x32_bf16(af[tm], bfr[tn], acc[tm][tn], 0, 0, 0);
    }
  }
#undef STAGE
  // C/D layout: col = lane&15, row = (lane>>4)*4 + reg   [guide §3, m89-verified]
#pragma unroll
  for (int tm = 0; tm < 4; ++tm) {
    int gr0 = row0 + wm * 64 + tm * 16 + q * 4;
#pragma unroll
    for (int tn = 0; tn < NC; ++tn) {
      int gc = col0 + wn * 16 * NC + tn * 16 + r;
#pragma unroll
      for (int p = 0; p < 4; ++p) {
        float vv = acc[tm][tn][p];
        if (RELU) vv = fmaxf(vv, 0.f);
        if (OUT_BF16)
          ((__hip_bfloat16*)Cv)[(size_t)(gr0 + p) * N + gc] = __float2bfloat16(vv);
        else {
          ((float*)Cv)[(size_t)(gr0 + p) * N + gc] = vv;
          if (MIRROR && gc > gr0 + p) ((float*)Cv)[(size_t)gc * N + (gr0 + p)] = vv;
        }
      }
    }
  }
}

// ---------------- 3a) scan upper triangle, per-block LDS compaction ----------
// Block = one row i; push only j >= i (S is bit-exact symmetric).
__global__ __launch_bounds__(256) void scan_borderline(const float* __restrict__ S,
                                                       int* __restrict__ count,
                                                       int* __restrict__ list) {
  __shared__ int lqueue[2048];
  __shared__ int lcount;
  __shared__ int gbase;
  if (threadIdx.x == 0) lcount = 0;
  __syncthreads();
  const int row = blockIdx.x;
  const int base_idx = row * 2048;
#pragma unroll
  for (int t = 0; t < 2; ++t) {
    int idx = base_idx + t * 1024 + threadIdx.x * 4;
    float4 v = *(const float4*)(S + idx);
    float vv[4] = {v.x, v.y, v.z, v.w};
#pragma unroll
    for (int u = 0; u < 4; ++u) {
      int j = (idx + u) & 2047;
      if (j >= row && fabsf(vv[u] - 0.1f) < WINDOW) {
        int p = atomicAdd(&lcount, 1);  // LDS atomic
        lqueue[p] = idx + u;
      }
    }
  }
  __syncthreads();
  if (threadIdx.x == 0) gbase = atomicAdd(count, lcount);
  __syncthreads();
  int n = lcount, g0 = gbase;
  for (int k = threadIdx.x; k < n; k += 256) {
    int pos = g0 + k;
    if (pos < LIST_CAP) list[pos] = lqueue[k];
  }
}

// ---------------- 3b) exact f32 repair, contiguous chunks, mirror write -----
__global__ void repair_borderline(float* __restrict__ S, const int* __restrict__ count,
                                  const int* __restrict__ list, const float* __restrict__ xpt,
                                  const float* __restrict__ w4, const float* __restrict__ norms) {
  const int lane = threadIdx.x & 63;
  const int wid = (blockIdx.x * 256 + threadIdx.x) >> 6;
  const int nw = gridDim.x * 4;
  int n = *count;
  if (n > LIST_CAP) n = LIST_CAP;
  const int chunk = (n + nw - 1) / nw;
  int k0 = wid * chunk;
  int k1 = k0 + chunk < n ? k0 + chunk : n;
  int cur_i = -1;
  float xiv[5];
  for (int k = k0; k < k1; ++k) {
    int e = list[k];
    int i = e >> 11, j = e & 2047;
    if (i != cur_i) {  // list is row-clustered: xi reused across same-i runs
      const float* xi = xpt + i * EPT;
#pragma unroll
      for (int t = 0; t < 5; ++t) {
        int idx = lane + 64 * t;
        xiv[t] = idx < EPT ? xi[idx] : 0.f;
      }
      cur_i = i;
    }
    const float* xj = xpt + j * EPT;
    float xjv[5];
#pragma unroll
    for (int t = 0; t < 5; ++t) {
      int idx = lane + 64 * t;
      xjv[t] = idx < EPT ? xj[idx] : 0.f;
    }
    float accv = 0.f;
#pragma unroll
    for (int h = 0; h < H_DIM; ++h) {
      float ph = 0.f;
#pragma unroll
      for (int t = 0; t < 5; ++t) {
        int idx = lane + 64 * t;
        if (idx < EPT) ph += xiv[t] * xjv[t] * w4[h * EPT + idx];
      }
      float invn = 1.f / (norms[i * H_DIM + h] * norms[j * H_DIM + h]);
      accv += ph * invn;
    }
#pragma unroll
    for (int o = 32; o >= 1; o >>= 1) accv += __shfl_xor(accv, o, 64);
    if (lane == 0) {
      float val = accv * (1.f / 16.f);
      S[(size_t)i * L_DIM + j] = val;
      S[(size_t)j * L_DIM + i] = val;  // symmetric twin
    }
  }
}

// ---------------- 4) thresholded row softmax -> bf16 adj ----------------
__global__ void softmax_kernel(const float* __restrict__ S, __hip_bfloat16* __restrict__ adj) {
  __shared__ float red[4];
  const int row = blockIdx.x;
  const float* s = S + (size_t)row * L_DIM;
  const int tid = threadIdx.x;
  float m = -1e30f;
  for (int j = tid; j < L_DIM; j += 256) {
    float v = s[j];
    if (v >= 0.1f && v > m) m = v;
  }
#pragma unroll
  for (int o = 32; o >= 1; o >>= 1) m = fmaxf(m, __shfl_xor(m, o, 64));
  if ((tid & 63) == 0) red[tid >> 6] = m;
  __syncthreads();
  m = fmaxf(fmaxf(red[0], red[1]), fmaxf(red[2], red[3]));
  float sum = 0.f;
  for (int j = tid; j < L_DIM; j += 256) {
    float v = s[j];
    if (v >= 0.1f) sum += __expf(v - m);
  }
#pragma unroll
  for (int o = 32; o >= 1; o >>= 1) sum += __shfl_xor(sum, o, 64);
  __syncthreads();
  if ((tid & 63) == 0) red[tid >> 6] = sum;
  __syncthreads();
  sum = red[0] + red[1] + red[2] + red[3];
  float inv = 1.f / sum;
  for (int j = tid; j < L_DIM; j += 256) {
    float v = s[j];
    float a = (v >= 0.1f) ? __expf(v - m) * inv : 0.f;
    adj[(size_t)row * L_DIM + j] = __float2bfloat16(a);
  }
}

// ---------------- helpers ----------------
__global__ void cast_bf16_kernel(const float* __restrict__ in, __hip_bfloat16* __restrict__ out,
                                 int n) {
  int i = blockIdx.x * 256 + threadIdx.x;
  if (i < n) out[i] = __float2bfloat16(in[i]);
}

template <typename T>
__global__ void transpose_bf16_kernel(const T* __restrict__ in, __hip_bfloat16* __restrict__ out,
                                      int R, int C) {
  __shared__ float tile[32][33];
  int c0 = blockIdx.x * 32, r0 = blockIdx.y * 32;
  int tx = threadIdx.x, ty = threadIdx.y;
  for (int i = ty; i < 32; i += 8) tile[i][tx] = (float)in[(size_t)(r0 + i) * C + c0 + tx];
  __syncthreads();
  for (int i = ty; i < 32; i += 8)
    out[(size_t)(c0 + i) * R + r0 + tx] = __float2bfloat16(tile[tx][i]);
}

extern "C" void kernel_launch(void* const* d_in, const int* in_sizes, int n_in, void* d_out,
                              int out_size, void* d_ws, size_t ws_size, hipStream_t stream) {
  const float* label = (const float*)d_in[0];  // [2048,512]
  const float* xpt = (const float*)d_in[1];    // [2048,300]
  const float* Wpt = (const float*)d_in[2];    // [16,300]
  const float* W0 = (const float*)d_in[3];     // [512,512]
  const float* W1 = (const float*)d_in[4];     // [512,512]
  float* out = (float*)d_out;                  // [2048,512]

  // ---- layout: identical envelope to R5 (peak 36,588,288 B, proven) ----
  char* ws = (char*)d_ws;
  __hip_bfloat16* Y = (__hip_bfloat16*)ws;              // [0, 19,660,800)
  float* S = (float*)(ws + 19660800);                   // 16,777,216 B
  float* norms = (float*)(ws + 36438016);               // 131,072 B
  float* w4 = (float*)(ws + 36569088);                  // 19,200 B -> end 36,588,288
  int* bl_count = (int*)(ws + 9437184);                 // inside dead Y, above adj
  int* bl_list = (int*)(ws + 9437696);                  // cap 2.5M ints, ends < 19.66MB
  __hip_bfloat16* adj = (__hip_bfloat16*)ws;            // reuses Y region
  char* tmp = ws + 19660800;                            // reuses S region after softmax
  __hip_bfloat16* Lbf = (__hip_bfloat16*)tmp;                 // 2MB
  __hip_bfloat16* W0t = (__hip_bfloat16*)(tmp + 2097152);     // 0.5MB
  __hip_bfloat16* W1t = (__hip_bfloat16*)(tmp + 2621440);     // 0.5MB
  __hip_bfloat16* T0t = (__hip_bfloat16*)(tmp + 3145728);     // 2MB [512x2048]
  __hip_bfloat16* X1 = (__hip_bfloat16*)(tmp + 5242880);      // 2MB [2048x512]
  __hip_bfloat16* T1t = (__hip_bfloat16*)(tmp + 7340032);     // 2MB -> tmp end 9,437,184

  compute_y_kernel<<<8192, 256, 0, stream>>>(xpt, Wpt, Y, norms);
  w4_kernel<<<19, 256, 0, stream>>>(Wpt, w4);
  // S = Y Y^T  [2048,2048], symmetric: 128x64 triangle tiles + mirror (R5-proven)
  gemm_bt<128, 64, false, false, true><<<dim3(32, 16), 256, 0, stream>>>(Y, Y, S, 2048, 2048, KDIM);
  // borderline: compact (upper-tri only, window 1.5e-3 proven) then repair
  hipMemsetAsync(bl_count, 0, 4, stream);
  scan_borderline<<<2048, 256, 0, stream>>>(S, bl_count, bl_list);
  repair_borderline<<<2048, 256, 0, stream>>>(S, bl_count, bl_list, xpt, w4, norms);
  softmax_kernel<<<2048, 256, 0, stream>>>(S, adj);  // adj overwrites Y region (Y dead)
  // GCN prep (S region dead now)
  cast_bf16_kernel<<<4096, 256, 0, stream>>>(label, Lbf, 2048 * 512);
  transpose_bf16_kernel<float><<<dim3(16, 16), dim3(32, 8), 0, stream>>>(W0, W0t, 512, 512);
  transpose_bf16_kernel<float><<<dim3(16, 16), dim3(32, 8), 0, stream>>>(W1, W1t, 512, 512);
  // T0t = (label@W0)^T = W0t * Lbf^T   [512 x 2048]  (replaces T0 gemm + transpose)
  gemm_bt<64, 64, false, true, false><<<dim3(32, 8), 256, 0, stream>>>(W0t, Lbf, T0t, 512, 2048, 512);
  // X1 = relu(adj @ T0) = relu(adj * T0t^T)   [2048 x 512] bf16
  gemm_bt<64, 64, true, true, false><<<dim3(8, 32), 256, 0, stream>>>(adj, T0t, X1, 2048, 512, 2048);
  // T1t = (X1@W1)^T = W1t * X1^T   [512 x 2048]
  gemm_bt<64, 64, false, true, false><<<dim3(32, 8), 256, 0, stream>>>(W1t, X1, T1t, 512, 2048, 512);
  // out = relu(adj @ T1) = relu(adj * T1t^T)   [2048 x 512] f32
  gemm_bt<64, 64, true, false, false><<<dim3(8, 32), 256, 0, stream>>>(adj, T1t, out, 2048, 512, 2048);
}

// Round 9
// 284.440 us; speedup vs baseline: 2.3771x; 1.1115x over previous
//
#include <hip/hip_runtime.h>
#include <hip/hip_bf16.h>

// L=2048, E=512, E_PT=300, H=16. All inputs f32. Output f32 [2048,512].
//
// R9 = R8 (proven 316us) + three local deltas:
//  - gram: 64x64 triangle tiles, grid(32,32) -> 528 blocks (~2.06/CU) vs
//    R8's 272 (1.06/CU, MfmaUtil 10.8%)
//  - WINDOW 5.5e-4 (13 sigma of measured-model gram error ~4e-5 std; R6/R7
//    crashes were aborts in prep-fusion/split-K code, not window-related)
//  - repair: software-pipelined xj prefetch (overlap ~900cyc miss w/ compute)
// Crash suspects prep1/prep2-fusion, split-K, combiners remain EXCLUDED.

typedef __attribute__((ext_vector_type(8))) short bf16x8;
typedef __attribute__((ext_vector_type(4))) float f32x4;

#define L_DIM 2048
#define EPT 300
#define H_DIM 16
#define KDIM 4800
#define WINDOW 5.5e-4f
#define LIST_CAP 2500000

// ---------------- 1) Y + norms ----------------
__global__ void compute_y_kernel(const float* __restrict__ xpt,
                                 const float* __restrict__ Wpt,
                                 __hip_bfloat16* __restrict__ Y,
                                 float* __restrict__ norms) {
  int gw = (blockIdx.x * 256 + threadIdx.x) >> 6;  // wave id = (i,h) pair
  int lane = threadIdx.x & 63;
  int i = gw >> 4, h = gw & 15;
  const float* x = xpt + i * EPT;
  const float* w = Wpt + h * EPT;
  float v[5];
  float ss = 0.f;
#pragma unroll
  for (int t = 0; t < 5; ++t) {
    int e = lane + 64 * t;
    float val = 0.f;
    if (e < EPT) {
      float we = w[e];
      val = x[e] * we * we;
    }
    v[t] = val;
    ss += val * val;
  }
#pragma unroll
  for (int o = 32; o >= 1; o >>= 1) ss += __shfl_xor(ss, o, 64);
  float n = fmaxf(sqrtf(ss), 1e-12f);
  if (lane == 0) norms[i * H_DIM + h] = n;
  float scale = 0.25f / n;  // 1/(norm*sqrt(H))
#pragma unroll
  for (int t = 0; t < 5; ++t) {
    int e = lane + 64 * t;
    if (e < EPT) Y[(size_t)i * KDIM + h * EPT + e] = __float2bfloat16(v[t] * scale);
  }
}

__global__ void w4_kernel(const float* __restrict__ Wpt, float* __restrict__ w4) {
  int i = blockIdx.x * 256 + threadIdx.x;
  if (i < H_DIM * EPT) {
    float w = Wpt[i];
    float w2 = w * w;
    w4[i] = w2 * w2;
  }
}

// ---------------- 2) bt-GEMM: C = A * B^T ----------------
// A: [M,K] bf16 rm, B: [N,K] bf16 rm. BM in {64,128}, BN=64 lane partition:
// 4 waves as (BM/64) x (4/(BM/64)); each wave 64 rows x (16*NC) cols.
// XOR-swizzled LDS: chunk c of row r stored at slot c^(r&7). Double-buffered.
template <int BM, int BN, bool RELU, bool OUT_BF16, bool MIRROR>
__global__ __launch_bounds__(256) void gemm_bt(const __hip_bfloat16* __restrict__ A,
                                               const __hip_bfloat16* __restrict__ B,
                                               void* __restrict__ Cv, int M, int N, int K) {
  constexpr int WMG = BM / 64;        // wave groups along M (1 or 2)
  constexpr int WNG = 4 / WMG;        // wave groups along N
  constexpr int NC = BN / (16 * WNG); // 16-col frags per wave
  const int row0 = blockIdx.y * BM, col0 = blockIdx.x * BN;
  if (MIRROR && col0 + BN <= row0) return;  // fully below diagonal
  __shared__ __attribute__((aligned(16))) __hip_bfloat16 As[2][BM * 64];
  __shared__ __attribute__((aligned(16))) __hip_bfloat16 Bs[2][BN * 64];
  const int tid = threadIdx.x;
  const int lane = tid & 63;
  const int wave = tid >> 6;
  const int wm = wave / WNG, wn = wave % WNG;
  const int r = lane & 15, q = lane >> 4;
  const int srow = tid >> 3;                       // staging row within 32-row group
  const int schunk = (tid & 7) ^ (srow & 7);       // swizzled source chunk

  f32x4 acc[4][NC];
#pragma unroll
  for (int a = 0; a < 4; ++a)
#pragma unroll
    for (int b = 0; b < NC; ++b) {
      f32x4 z = {0.f, 0.f, 0.f, 0.f};
      acc[a][b] = z;
    }

  const int niter = K >> 6;

#define STAGE(bufi, k0)                                                                       \
  {                                                                                           \
    _Pragma("unroll") for (int it = 0; it < BM / 32; ++it) {                                  \
      __builtin_amdgcn_global_load_lds(                                                       \
          (const __attribute__((address_space(1))) void*)(A + (size_t)(row0 + it * 32 + srow) * K + \
                                                          (k0) + schunk * 8),                 \
          (__attribute__((address_space(3))) void*)(&As[bufi][(it * 256 + tid) * 8]), 16, 0, 0); \
    }                                                                                         \
    _Pragma("unroll") for (int it = 0; it < BN / 32; ++it) {                                  \
      __builtin_amdgcn_global_load_lds(                                                       \
          (const __attribute__((address_space(1))) void*)(B + (size_t)(col0 + it * 32 + srow) * K + \
                                                          (k0) + schunk * 8),                 \
          (__attribute__((address_space(3))) void*)(&Bs[bufi][(it * 256 + tid) * 8]), 16, 0, 0); \
    }                                                                                         \
  }

  STAGE(0, 0)
  for (int k = 0; k < niter; ++k) {
    __syncthreads();  // drains stage(k) (vmcnt0) + all reads of buf (k+1)&1
    if (k + 1 < niter) STAGE((k + 1) & 1, (k + 1) << 6)
    const __hip_bfloat16* as = As[k & 1];
    const __hip_bfloat16* bs = Bs[k & 1];
#pragma unroll
    for (int kk = 0; kk < 2; ++kk) {
      const int ch = ((kk * 4 + q) ^ (r & 7)) * 8;  // swizzled read chunk
      bf16x8 af[4], bfr[NC];
#pragma unroll
      for (int t = 0; t < 4; ++t)
        af[t] = *(const bf16x8*)(as + (wm * 64 + t * 16 + r) * 64 + ch);
#pragma unroll
      for (int c = 0; c < NC; ++c)
        bfr[c] = *(const bf16x8*)(bs + (wn * 16 * NC + c * 16 + r) * 64 + ch);
#pragma unroll
      for (int tm = 0; tm < 4; ++tm)
#pragma unroll
        for (int tn = 0; tn < NC; ++tn)
          acc[tm][tn] = __builtin_amdgcn_mfma_f32_16x16x32_bf16(af[tm], bfr[tn], acc[tm][tn], 0, 0, 0);
    }
  }
#undef STAGE
  // C/D layout: col = lane&15, row = (lane>>4)*4 + reg   [guide §3, m89-verified]
#pragma unroll
  for (int tm = 0; tm < 4; ++tm) {
    int gr0 = row0 + wm * 64 + tm * 16 + q * 4;
#pragma unroll
    for (int tn = 0; tn < NC; ++tn) {
      int gc = col0 + wn * 16 * NC + tn * 16 + r;
#pragma unroll
      for (int p = 0; p < 4; ++p) {
        float vv = acc[tm][tn][p];
        if (RELU) vv = fmaxf(vv, 0.f);
        if (OUT_BF16)
          ((__hip_bfloat16*)Cv)[(size_t)(gr0 + p) * N + gc] = __float2bfloat16(vv);
        else {
          ((float*)Cv)[(size_t)(gr0 + p) * N + gc] = vv;
          if (MIRROR && gc > gr0 + p) ((float*)Cv)[(size_t)gc * N + (gr0 + p)] = vv;
        }
      }
    }
  }
}

// ---------------- 3a) scan upper triangle, per-block LDS compaction ----------
// Block = one row i; push only j >= i (S is bit-exact symmetric).
__global__ __launch_bounds__(256) void scan_borderline(const float* __restrict__ S,
                                                       int* __restrict__ count,
                                                       int* __restrict__ list) {
  __shared__ int lqueue[2048];
  __shared__ int lcount;
  __shared__ int gbase;
  if (threadIdx.x == 0) lcount = 0;
  __syncthreads();
  const int row = blockIdx.x;
  const int base_idx = row * 2048;
#pragma unroll
  for (int t = 0; t < 2; ++t) {
    int idx = base_idx + t * 1024 + threadIdx.x * 4;
    float4 v = *(const float4*)(S + idx);
    float vv[4] = {v.x, v.y, v.z, v.w};
#pragma unroll
    for (int u = 0; u < 4; ++u) {
      int j = (idx + u) & 2047;
      if (j >= row && fabsf(vv[u] - 0.1f) < WINDOW) {
        int p = atomicAdd(&lcount, 1);  // LDS atomic
        lqueue[p] = idx + u;
      }
    }
  }
  __syncthreads();
  if (threadIdx.x == 0) gbase = atomicAdd(count, lcount);
  __syncthreads();
  int n = lcount, g0 = gbase;
  for (int k = threadIdx.x; k < n; k += 256) {
    int pos = g0 + k;
    if (pos < LIST_CAP) list[pos] = lqueue[k];
  }
}

// ---------------- 3b) exact f32 repair, pipelined xj prefetch ----------------
__global__ void repair_borderline(float* __restrict__ S, const int* __restrict__ count,
                                  const int* __restrict__ list, const float* __restrict__ xpt,
                                  const float* __restrict__ w4, const float* __restrict__ norms) {
  const int lane = threadIdx.x & 63;
  const int wid = (blockIdx.x * 256 + threadIdx.x) >> 6;
  const int nw = gridDim.x * 4;
  int n = *count;
  if (n > LIST_CAP) n = LIST_CAP;
  const int chunk = (n + nw - 1) / nw;
  int k0 = wid * chunk;
  int k1 = k0 + chunk < n ? k0 + chunk : n;
  if (k0 >= k1) return;
  // prime the pipeline: entry k0
  int e = list[k0];
  int i = e >> 11, j = e & 2047;
  float xiv[5], xjv[5];
  {
    const float* xi = xpt + i * EPT;
    const float* xj = xpt + j * EPT;
#pragma unroll
    for (int t = 0; t < 5; ++t) {
      int idx = lane + 64 * t;
      xiv[t] = idx < EPT ? xi[idx] : 0.f;
      xjv[t] = idx < EPT ? xj[idx] : 0.f;
    }
  }
  int cur_i = i;
  for (int k = k0; k < k1; ++k) {
    // prefetch next entry's xj while computing current
    int en = (k + 1 < k1) ? list[k + 1] : e;
    int in2 = en >> 11, jn = en & 2047;
    const float* xjp = xpt + jn * EPT;
    float xjn[5];
#pragma unroll
    for (int t = 0; t < 5; ++t) {
      int idx = lane + 64 * t;
      xjn[t] = idx < EPT ? xjp[idx] : 0.f;
    }
    // compute current (i, j) exactly in f32
    float pre[5];
#pragma unroll
    for (int t = 0; t < 5; ++t) pre[t] = xiv[t] * xjv[t];
    float accv = 0.f;
#pragma unroll
    for (int h = 0; h < H_DIM; ++h) {
      float ph = 0.f;
#pragma unroll
      for (int t = 0; t < 5; ++t) {
        int idx = lane + 64 * t;
        if (idx < EPT) ph += pre[t] * w4[h * EPT + idx];
      }
      float invn = 1.f / (norms[i * H_DIM + h] * norms[j * H_DIM + h]);
      accv += ph * invn;
    }
#pragma unroll
    for (int o = 32; o >= 1; o >>= 1) accv += __shfl_xor(accv, o, 64);
    if (lane == 0) {
      float val = accv * (1.f / 16.f);
      S[(size_t)i * L_DIM + j] = val;
      S[(size_t)j * L_DIM + i] = val;  // symmetric twin
    }
    // advance pipeline
    if (in2 != cur_i) {  // rare: i changes within a chunk
      const float* xi = xpt + in2 * EPT;
#pragma unroll
      for (int t = 0; t < 5; ++t) {
        int idx = lane + 64 * t;
        xiv[t] = idx < EPT ? xi[idx] : 0.f;
      }
      cur_i = in2;
    }
    i = in2;
    j = jn;
    e = en;
#pragma unroll
    for (int t = 0; t < 5; ++t) xjv[t] = xjn[t];
  }
}

// ---------------- 4) thresholded row softmax -> bf16 adj ----------------
__global__ void softmax_kernel(const float* __restrict__ S, __hip_bfloat16* __restrict__ adj) {
  __shared__ float red[4];
  const int row = blockIdx.x;
  const float* s = S + (size_t)row * L_DIM;
  const int tid = threadIdx.x;
  float m = -1e30f;
  for (int j = tid; j < L_DIM; j += 256) {
    float v = s[j];
    if (v >= 0.1f && v > m) m = v;
  }
#pragma unroll
  for (int o = 32; o >= 1; o >>= 1) m = fmaxf(m, __shfl_xor(m, o, 64));
  if ((tid & 63) == 0) red[tid >> 6] = m;
  __syncthreads();
  m = fmaxf(fmaxf(red[0], red[1]), fmaxf(red[2], red[3]));
  float sum = 0.f;
  for (int j = tid; j < L_DIM; j += 256) {
    float v = s[j];
    if (v >= 0.1f) sum += __expf(v - m);
  }
#pragma unroll
  for (int o = 32; o >= 1; o >>= 1) sum += __shfl_xor(sum, o, 64);
  __syncthreads();
  if ((tid & 63) == 0) red[tid >> 6] = sum;
  __syncthreads();
  sum = red[0] + red[1] + red[2] + red[3];
  float inv = 1.f / sum;
  for (int j = tid; j < L_DIM; j += 256) {
    float v = s[j];
    float a = (v >= 0.1f) ? __expf(v - m) * inv : 0.f;
    adj[(size_t)row * L_DIM + j] = __float2bfloat16(a);
  }
}

// ---------------- helpers ----------------
__global__ void cast_bf16_kernel(const float* __restrict__ in, __hip_bfloat16* __restrict__ out,
                                 int n) {
  int i = blockIdx.x * 256 + threadIdx.x;
  if (i < n) out[i] = __float2bfloat16(in[i]);
}

template <typename T>
__global__ void transpose_bf16_kernel(const T* __restrict__ in, __hip_bfloat16* __restrict__ out,
                                      int R, int C) {
  __shared__ float tile[32][33];
  int c0 = blockIdx.x * 32, r0 = blockIdx.y * 32;
  int tx = threadIdx.x, ty = threadIdx.y;
  for (int i = ty; i < 32; i += 8) tile[i][tx] = (float)in[(size_t)(r0 + i) * C + c0 + tx];
  __syncthreads();
  for (int i = ty; i < 32; i += 8)
    out[(size_t)(c0 + i) * R + r0 + tx] = __float2bfloat16(tile[tx][i]);
}

extern "C" void kernel_launch(void* const* d_in, const int* in_sizes, int n_in, void* d_out,
                              int out_size, void* d_ws, size_t ws_size, hipStream_t stream) {
  const float* label = (const float*)d_in[0];  // [2048,512]
  const float* xpt = (const float*)d_in[1];    // [2048,300]
  const float* Wpt = (const float*)d_in[2];    // [16,300]
  const float* W0 = (const float*)d_in[3];     // [512,512]
  const float* W1 = (const float*)d_in[4];     // [512,512]
  float* out = (float*)d_out;                  // [2048,512]

  // ---- layout: identical envelope to R5/R8 (peak 36,588,288 B, proven) ----
  char* ws = (char*)d_ws;
  __hip_bfloat16* Y = (__hip_bfloat16*)ws;              // [0, 19,660,800)
  float* S = (float*)(ws + 19660800);                   // 16,777,216 B
  float* norms = (float*)(ws + 36438016);               // 131,072 B
  float* w4 = (float*)(ws + 36569088);                  // 19,200 B -> end 36,588,288
  int* bl_count = (int*)(ws + 9437184);                 // inside dead Y, above adj
  int* bl_list = (int*)(ws + 9437696);                  // cap 2.5M ints, ends < 19.66MB
  __hip_bfloat16* adj = (__hip_bfloat16*)ws;            // reuses Y region
  char* tmp = ws + 19660800;                            // reuses S region after softmax
  __hip_bfloat16* Lbf = (__hip_bfloat16*)tmp;                 // 2MB
  __hip_bfloat16* W0t = (__hip_bfloat16*)(tmp + 2097152);     // 0.5MB
  __hip_bfloat16* W1t = (__hip_bfloat16*)(tmp + 2621440);     // 0.5MB
  __hip_bfloat16* T0t = (__hip_bfloat16*)(tmp + 3145728);     // 2MB [512x2048]
  __hip_bfloat16* X1 = (__hip_bfloat16*)(tmp + 5242880);      // 2MB [2048x512]
  __hip_bfloat16* T1t = (__hip_bfloat16*)(tmp + 7340032);     // 2MB -> tmp end 9,437,184

  compute_y_kernel<<<8192, 256, 0, stream>>>(xpt, Wpt, Y, norms);
  w4_kernel<<<19, 256, 0, stream>>>(Wpt, w4);
  // S = Y Y^T  [2048,2048], symmetric: 64x64 triangle tiles (528 blocks) + mirror
  gemm_bt<64, 64, false, false, true><<<dim3(32, 32), 256, 0, stream>>>(Y, Y, S, 2048, 2048, KDIM);
  // borderline: compact (upper-tri, window 5.5e-4) then repair (pipelined)
  hipMemsetAsync(bl_count, 0, 4, stream);
  scan_borderline<<<2048, 256, 0, stream>>>(S, bl_count, bl_list);
  repair_borderline<<<2048, 256, 0, stream>>>(S, bl_count, bl_list, xpt, w4, norms);
  softmax_kernel<<<2048, 256, 0, stream>>>(S, adj);  // adj overwrites Y region (Y dead)
  // GCN prep (S region dead now)
  cast_bf16_kernel<<<4096, 256, 0, stream>>>(label, Lbf, 2048 * 512);
  transpose_bf16_kernel<float><<<dim3(16, 16), dim3(32, 8), 0, stream>>>(W0, W0t, 512, 512);
  transpose_bf16_kernel<float><<<dim3(16, 16), dim3(32, 8), 0, stream>>>(W1, W1t, 512, 512);
  // T0t = (label@W0)^T = W0t * Lbf^T   [512 x 2048]
  gemm_bt<64, 64, false, true, false><<<dim3(32, 8), 256, 0, stream>>>(W0t, Lbf, T0t, 512, 2048, 512);
  // X1 = relu(adj @ T0) = relu(adj * T0t^T)   [2048 x 512] bf16
  gemm_bt<64, 64, true, true, false><<<dim3(8, 32), 256, 0, stream>>>(adj, T0t, X1, 2048, 512, 2048);
  // T1t = (X1@W1)^T = W1t * X1^T   [512 x 2048]
  gemm_bt<64, 64, false, true, false><<<dim3(32, 8), 256, 0, stream>>>(W1t, X1, T1t, 512, 2048, 512);
  // out = relu(adj @ T1) = relu(adj * T1t^T)   [2048 x 512] f32
  gemm_bt<64, 64, true, false, false><<<dim3(8, 32), 256, 0, stream>>>(adj, T1t, out, 2048, 512, 2048);
}